// Round 10
// baseline (203.493 us; speedup 1.0000x reference)
//
#include <hip/hip_runtime.h>
#include <hip/hip_bf16.h>
#include <math.h>

#define NN 50000
#define NE 800000
#define ETOT (NE + NN)      // 850000, self-loops appended after edges
#define CLS 40
#define CLSP 48             // layer-2 channels padded to 48
#define NEG 0.2f
#define MTILES (NN / 16)    // 3125 exact
#define GB1 ((MTILES + 3) / 4)   // 782 gemm blocks
#define PREPB 176           // prep blocks: ceil(45056/256)
#define NBUCK 196           // ceil(50000/256) dst buckets of 256 nodes
#define BCAP 8192           // per-bucket capacity (mean 4352, sd ~64)
#define EB 4096             // edges per scatter block
#define KAB ((ETOT + EB - 1) / EB)   // 208
#define NODEB (NN / 8)      // 6250 blocks for node_l2: 4 waves/block, 2 nodes/wave

#define L2E 1.44269504088896f
#define C06 (0.6f * L2E)
#define C04 (0.4f * L2E)

typedef __hip_bfloat16 bf16;
typedef __attribute__((ext_vector_type(8))) __bf16 bf16x8;
typedef __attribute__((ext_vector_type(4))) float f32x4;
typedef __attribute__((ext_vector_type(2))) float f32x2;
struct U3 { unsigned x, y, z; };   // 12B, 4-aligned

__device__ __forceinline__ bf16x8 cvt8(f32x4 a, f32x4 b) {
    bf16x8 r;
    r[0] = (__bf16)a[0]; r[1] = (__bf16)a[1]; r[2] = (__bf16)a[2]; r[3] = (__bf16)a[3];
    r[4] = (__bf16)b[0]; r[5] = (__bf16)b[1]; r[6] = (__bf16)b[2]; r[7] = (__bf16)b[3];
    return r;
}
// 2 packed bf16 (one u32) -> f32x2 (register pair feeding v_pk_* ops)
__device__ __forceinline__ f32x2 unpk2(unsigned u) {
    f32x2 r;
    r.x = __uint_as_float(u << 16);
    r.y = __uint_as_float(u & 0xffff0000u);
    return r;
}

// 256-entry exclusive scan (4 waves). Returns exclusive prefix of v.
__device__ __forceinline__ unsigned scan256(unsigned v, unsigned* wsum) {
    int t = threadIdx.x;
    int lane = t & 63, w = t >> 6;
    unsigned inc = v;
#pragma unroll
    for (int d = 1; d < 64; d <<= 1) {
        unsigned x = __shfl_up(inc, d);
        if (lane >= d) inc += x;
    }
    if (lane == 63) wsum[w] = inc;
    __syncthreads();
    unsigned woff = 0;
#pragma unroll
    for (int i = 0; i < 4; i++) woff += (i < w) ? wsum[i] : 0;
    return woff + inc - v;
}

// ---- K1: weight prep (fp32->bf16 transposed) + zero bucket cursors. ----
__global__ __launch_bounds__(256) void prep(
        const float* __restrict__ w1l, const float* __restrict__ w1r,
        const float* __restrict__ w2l, const float* __restrict__ w2r,
        bf16* __restrict__ wT1, bf16* __restrict__ wT2,
        int* __restrict__ bcursor) {
    int t = blockIdx.x * 256 + threadIdx.x;
    if (t < NBUCK) bcursor[t] = 0;
    if (t < 2 * 128 * 128) {
        int m = t >> 14;
        int idx = t & 16383;
        int n = idx >> 7, k = idx & 127;
        const float* w = m ? w1r : w1l;
        wT1[t] = __float2bfloat16(w[k * 128 + n]);
    } else if (t < 2 * 128 * 128 + 2 * CLSP * 128) {
        int u = t - 2 * 128 * 128;
        int m = u / (CLSP * 128);
        int idx = u % (CLSP * 128);
        int n = idx >> 7, k = idx & 127;
        const float* w = m ? w2r : w2l;
        wT2[u] = __float2bfloat16((n < CLS) ? w[k * CLS + n] : 0.0f);
    }
}

// ---- K2: GEMM1 dual (LDS-staged weights) || LDS-binned edge scatter. ----
// One 64KB shared buffer, carved per branch. The gemm branch stages the full
// 2x128x128 bf16 weight table in LDS (XOR-swizzled, col ^= (row&7)<<4, applied
// on BOTH write and read) so the inner loop's weight reads are ds_read_b128
// instead of serialized L1/L2 round-trips (the measured 42us latency wall).
__global__ __launch_bounds__(256) void gemm1_scatter(
        const float* __restrict__ x, const bf16* __restrict__ wT,
        bf16* __restrict__ outL, bf16* __restrict__ outR,
        const int* __restrict__ ei, int* __restrict__ bcursor,
        uint2* __restrict__ tmp) {
    __shared__ __align__(16) char smem[65536];
    if ((int)blockIdx.x < GB1) {
        // ---- stage weights: 4096 x 16B chunks, swizzled ----
        const uint4* wsrc = (const uint4*)wT;
#pragma unroll
        for (int i = 0; i < 16; i++) {
            int idx = i * 256 + threadIdx.x;
            uint4 v = wsrc[idx];
            int r = idx >> 4;                  // 256B row
            int c = (idx & 15) << 4;           // byte col
            *(uint4*)(smem + r * 256 + (c ^ ((r & 7) << 4))) = v;
        }
        __syncthreads();
        int wave = threadIdx.x >> 6;
        int lane = threadIdx.x & 63;
        int tile = blockIdx.x * 4 + wave;
        if (tile >= MTILES) return;
        int row0 = tile * 16;
        int l16 = lane & 15, quad = lane >> 4;
        f32x4 z = {0.f, 0.f, 0.f, 0.f};
        f32x4 accl[8], accr[8];
#pragma unroll
        for (int i = 0; i < 8; i++) { accl[i] = z; accr[i] = z; }
        const float* xrow = x + (size_t)(row0 + l16) * 128 + quad * 8;
#pragma unroll
        for (int k0 = 0; k0 < 128; k0 += 32) {
            f32x4 a0 = *reinterpret_cast<const f32x4*>(xrow + k0);
            f32x4 a1v = *reinterpret_cast<const f32x4*>(xrow + k0 + 4);
            bf16x8 a = cvt8(a0, a1v);
            int cc = k0 * 2 + quad * 16;       // byte col of this lane's 16B
#pragma unroll
            for (int ct = 0; ct < 8; ct++) {
                int rl = ct * 16 + l16;        // wl row
                int sw = cc ^ ((l16 & 7) << 4);
                bf16x8 bl = *(const bf16x8*)(smem + rl * 256 + sw);
                bf16x8 br = *(const bf16x8*)(smem + 32768 + rl * 256 + sw);
                accl[ct] = __builtin_amdgcn_mfma_f32_16x16x32_bf16(a, bl, accl[ct], 0, 0, 0);
                accr[ct] = __builtin_amdgcn_mfma_f32_16x16x32_bf16(a, br, accr[ct], 0, 0, 0);
            }
        }
#pragma unroll
        for (int ct = 0; ct < 8; ct++)
#pragma unroll
            for (int r = 0; r < 4; r++) {
                size_t o = (size_t)(row0 + quad * 4 + r) * 128 + ct * 16 + l16;
                outL[o] = __float2bfloat16(accl[ct][r]);
                outR[o] = __float2bfloat16(accr[ct][r]);
            }
    } else {
        unsigned* hist   = (unsigned*)smem;                 // 1KB
        unsigned* lstart = (unsigned*)(smem + 1024);        // 1KB
        unsigned* lcur   = (unsigned*)(smem + 2048);        // 1KB
        unsigned* gbase  = (unsigned*)(smem + 3072);        // 1KB
        unsigned* wsum   = (unsigned*)(smem + 4096);        // 16B
        uint2*    binned = (uint2*)(smem + 4608);           // 32KB
        unsigned* target = (unsigned*)(smem + 37376);       // 16KB
        int t = threadIdx.x;
        int e0 = ((int)blockIdx.x - GB1) * EB;
        hist[t] = 0;
        __syncthreads();
        int srcs[16], dsts[16];
#pragma unroll
        for (int i = 0; i < 16; i++) {
            int e = e0 + i * 256 + t;
            if (e < ETOT) {
                int s, d;
                if (e < NE) { s = ei[e]; d = ei[NE + e]; }
                else        { s = d = e - NE; }
                srcs[i] = s; dsts[i] = d;
                atomicAdd(&hist[d >> 8], 1u);
            } else dsts[i] = -1;
        }
        __syncthreads();
        unsigned v = hist[t];
        unsigned excl = scan256(v, wsum);
        lstart[t] = excl;
        lcur[t] = 0;
        __syncthreads();
        if (t < NBUCK && v > 0)
            gbase[t] = (unsigned)atomicAdd(&bcursor[t], (int)v) + (unsigned)t * BCAP;
        __syncthreads();
#pragma unroll
        for (int i = 0; i < 16; i++) {
            int d = dsts[i];
            if (d >= 0) {
                int bk = d >> 8;
                unsigned p = atomicAdd(&lcur[bk], 1u);
                unsigned slot = lstart[bk] + p;
                binned[slot] = make_uint2((unsigned)srcs[i], (unsigned)d);
                target[slot] = gbase[bk] + p;
            }
        }
        __syncthreads();
        int tot = min(EB, ETOT - e0);
        for (int s = t; s < tot; s += 256)
            tmp[target[s]] = binned[s];
    }
}

// ---- KB: per-bucket node sort -> csr_src + start/deg + padded row64. ----
// Scattered permutation stays in LDS; all global writes are coalesced streams.
// row64[node][lane] = csr[start+min(lane,deg-1)] pre-clamps the first 64
// sources per node so the node kernels' startup loads are all INDEPENDENT
// (no startA -> csr dependent chain).
__global__ __launch_bounds__(256) void bucket_sort(const int* __restrict__ bcursor,
                                                   const uint2* __restrict__ tmp,
                                                   int* __restrict__ csr_src,
                                                   int* __restrict__ startA,
                                                   int* __restrict__ degA,
                                                   int* __restrict__ row64) {
    __shared__ unsigned hist[256];
    __shared__ unsigned lstart[256];
    __shared__ unsigned lcur[256];
    __shared__ unsigned wsum[4];
    __shared__ int vals[BCAP];          // 32 KB LDS staging
    int b = blockIdx.x, t = threadIdx.x;
    int cnt = bcursor[b];
    hist[t] = 0;
    __syncthreads();
    const uint2* seg = tmp + (size_t)b * BCAP;
    for (int s = t; s < cnt; s += 256)
        atomicAdd(&hist[seg[s].y & 255], 1u);
    __syncthreads();
    unsigned v = hist[t];
    unsigned excl = scan256(v, wsum);
    lstart[t] = excl;
    lcur[t] = excl;
    int node = b * 256 + t;
    if (node < NN) {
        startA[node] = b * BCAP + (int)excl;
        degA[node] = (int)v;
    }
    __syncthreads();
    for (int s = t; s < cnt; s += 256) {
        uint2 p = seg[s];                       // L2-hot re-read
        unsigned pos = atomicAdd(&lcur[p.y & 255], 1u);
        vals[pos] = (int)p.x;                   // scattered write stays in LDS
    }
    __syncthreads();
    int* cbase = csr_src + (size_t)b * BCAP;
    for (int s = t; s < cnt; s += 256)
        cbase[s] = vals[s];                     // coalesced global stream
    // padded first-64 adjacency: 4 nodes per iteration, 64 lanes per node
    int slot = t & 63;
#pragma unroll 4
    for (int i = 0; i < 64; i++) {
        int n2 = (t >> 6) + i * 4;
        int node2 = b * 256 + n2;
        if (node2 < NN) {
            int d2 = (int)hist[n2];
            int e2 = (int)lstart[n2];
            row64[(size_t)node2 * 64 + slot] = vals[e2 + min(slot, d2 - 1)];
        }
    }
}

// ---- K5: layer 1 fused. ONE node/wave, 16 lanes/edge, up to 32 edges in
// flight. Startup loads {deg, row64, xr} are all independent (row64 removes
// the startA->csr chain). Packed-fp32 math: leaky(v)=0.6v+0.4|v|; log2e
// prefolded; accumulate w*t with -xr correction.
struct L1S { float s; f32x2 acc[4]; };
__device__ __forceinline__ void l1_consume(uint4 u, bool valid, const f32x2* xrp,
                                           const f32x2* a06, const float* a04, L1S& st) {
    f32x2 t0 = unpk2(u.x) + xrp[0];
    f32x2 t1 = unpk2(u.y) + xrp[1];
    f32x2 t2 = unpk2(u.z) + xrp[2];
    f32x2 t3 = unpk2(u.w) + xrp[3];
    f32x2 ep = t0 * a06[0];
    ep = __builtin_elementwise_fma(t1, a06[1], ep);
    ep = __builtin_elementwise_fma(t2, a06[2], ep);
    ep = __builtin_elementwise_fma(t3, a06[3], ep);
    float e0 = fmaf(a04[1], fabsf(t0.y), a04[0] * fabsf(t0.x));
    e0 = fmaf(a04[2], fabsf(t1.x), e0);
    e0 = fmaf(a04[3], fabsf(t1.y), e0);
    float e1 = fmaf(a04[5], fabsf(t2.y), a04[4] * fabsf(t2.x));
    e1 = fmaf(a04[6], fabsf(t3.x), e1);
    e1 = fmaf(a04[7], fabsf(t3.y), e1);
    float e = (ep.x + ep.y) + (e0 + e1);
    e += __shfl_xor(e, 1);
    e += __shfl_xor(e, 2);          // per-head logit (4-lane quad)
    float w = valid ? __builtin_amdgcn_exp2f(e) : 0.f;
    st.s += w;
    f32x2 wv = {w, w};
    st.acc[0] = __builtin_elementwise_fma(wv, t0, st.acc[0]);
    st.acc[1] = __builtin_elementwise_fma(wv, t1, st.acc[1]);
    st.acc[2] = __builtin_elementwise_fma(wv, t2, st.acc[2]);
    st.acc[3] = __builtin_elementwise_fma(wv, t3, st.acc[3]);
}

__global__ __launch_bounds__(256) void node_l1(const int* __restrict__ startA,
                                               const int* __restrict__ degA,
                                               const int* __restrict__ csr_src,
                                               const int* __restrict__ row64,
                                               const bf16* __restrict__ xl,
                                               const bf16* __restrict__ xr,
                                               const float* __restrict__ a1,
                                               const float* __restrict__ b1,
                                               bf16* __restrict__ hb) {
    int wid = (blockIdx.x * 256 + threadIdx.x) >> 6;
    int lane = threadIdx.x & 63;
    int g = lane >> 4, t = lane & 15;
    unsigned cB = (unsigned)t * 16;
    // three INDEPENDENT startup loads (no dependent chain)
    int deg = degA[wid];
    unsigned rowB = (unsigned)row64[blockIdx.x * 256 + threadIdx.x] << 8;
    const char* xlb = (const char*)xl;
    f32x2 xrp[4];
    {
        uint4 raw = *(const uint4*)((const char*)xr + ((unsigned)wid << 8) + cB);
        xrp[0] = unpk2(raw.x); xrp[1] = unpk2(raw.y);
        xrp[2] = unpk2(raw.z); xrp[3] = unpk2(raw.w);
    }
    f32x2 a06[4];
    float a04[8];
    {
        f32x4 lo = *reinterpret_cast<const f32x4*>(a1 + t * 8);
        f32x4 hi = *reinterpret_cast<const f32x4*>(a1 + t * 8 + 4);
        float af[8];
#pragma unroll
        for (int k = 0; k < 4; k++) { af[k] = lo[k]; af[k + 4] = hi[k]; }
#pragma unroll
        for (int j = 0; j < 4; j++) {
            a06[j].x = af[2 * j] * C06;
            a06[j].y = af[2 * j + 1] * C06;
        }
#pragma unroll
        for (int k = 0; k < 8; k++) a04[k] = af[k] * C04;
    }
    L1S st; st.s = 0.f;
    f32x2 z2 = {0.f, 0.f};
#pragma unroll
    for (int k = 0; k < 4; k++) st.acc[k] = z2;
    int nb = (deg + 3) >> 2;      // 4 edges per batch, one per 16-lane group
    uint4 u[8];
#pragma unroll
    for (int i = 0; i < 4; i++) {
        int pp = min(i * 4 + g, deg - 1);     // <= 31, shfl-safe
        u[i] = *(const uint4*)(xlb + (__shfl(rowB, pp) + cB));
    }
    if (nb > 4) {
#pragma unroll
        for (int i = 4; i < 8; i++) {
            int pp = min(i * 4 + g, deg - 1); // <= 31, shfl-safe
            u[i] = *(const uint4*)(xlb + (__shfl(rowB, pp) + cB));
        }
    }
    l1_consume(u[0], g < deg, xrp, a06, a04, st);
    if (nb > 1) l1_consume(u[1], 4 + g < deg, xrp, a06, a04, st);
    if (nb > 2) l1_consume(u[2], 8 + g < deg, xrp, a06, a04, st);
    if (nb > 3) l1_consume(u[3], 12 + g < deg, xrp, a06, a04, st);
    if (nb > 4) {
        l1_consume(u[4], 16 + g < deg, xrp, a06, a04, st);
        if (nb > 5) l1_consume(u[5], 20 + g < deg, xrp, a06, a04, st);
        if (nb > 6) l1_consume(u[6], 24 + g < deg, xrp, a06, a04, st);
        if (nb > 7) l1_consume(u[7], 28 + g < deg, xrp, a06, a04, st);
        if (nb > 8) {
            // deg > 32: rare serial fallback. csr/startA only touched here.
            int j0t = (deg > 64) ? startA[wid] : 0;
            for (int b = 8; b < nb; b++) {
                int p = b * 4 + g;
                bool valid = p < deg;
                int pp = valid ? p : deg - 1;
                unsigned o = __shfl(rowB, min(pp, 63)) + cB;
                if (pp >= 64) o = (((unsigned)csr_src[j0t + pp]) << 8) + cB;
                uint4 uu = *(const uint4*)(xlb + o);
                l1_consume(uu, valid, xrp, a06, a04, st);
            }
        }
    }
#pragma unroll
    for (int d = 16; d < 64; d <<= 1) {
        st.s += __shfl_xor(st.s, d);
#pragma unroll
        for (int k = 0; k < 4; k++) {
            st.acc[k].x += __shfl_xor(st.acc[k].x, d);
            st.acc[k].y += __shfl_xor(st.acc[k].y, d);
        }
    }
    if (g == 0) {
        float inv = 1.f / st.s;
        unsigned pk[4];
#pragma unroll
        for (int k = 0; k < 4; k++) {
            float o0 = st.acc[k].x * inv - xrp[k].x + b1[t * 8 + 2 * k];
            float o1 = st.acc[k].y * inv - xrp[k].y + b1[t * 8 + 2 * k + 1];
            o0 = o0 > 0.f ? o0 : __expf(o0) - 1.f;
            o1 = o1 > 0.f ? o1 : __expf(o1) - 1.f;
            bf16 r0 = __float2bfloat16(o0), r1 = __float2bfloat16(o1);
            pk[k] = (unsigned)*reinterpret_cast<unsigned short*>(&r0) |
                    ((unsigned)*reinterpret_cast<unsigned short*>(&r1) << 16);
        }
        uint4 w4 = {pk[0], pk[1], pk[2], pk[3]};
        *(uint4*)((char*)hb + ((unsigned)wid << 8) + cB) = w4;
    }
}

// ---- K6: GEMM2 dual (LDS-staged 24KB weights, same swizzle scheme). ----
__global__ __launch_bounds__(256) void gemm2(const bf16* __restrict__ h,
                                             const bf16* __restrict__ wT,
                                             bf16* __restrict__ outL,
                                             bf16* __restrict__ outR) {
    __shared__ __align__(16) char smem[24576];   // 96 rows x 256B
    const uint4* wsrc = (const uint4*)wT;
#pragma unroll
    for (int i = 0; i < 6; i++) {
        int idx = i * 256 + threadIdx.x;
        uint4 v = wsrc[idx];
        int r = idx >> 4;
        int c = (idx & 15) << 4;
        *(uint4*)(smem + r * 256 + (c ^ ((r & 7) << 4))) = v;
    }
    __syncthreads();
    int wave = threadIdx.x >> 6;
    int lane = threadIdx.x & 63;
    int tile = blockIdx.x * 4 + wave;
    if (tile >= MTILES) return;
    int row0 = tile * 16;
    int l16 = lane & 15, quad = lane >> 4;
    f32x4 z = {0.f, 0.f, 0.f, 0.f};
    f32x4 accl[3], accr[3];
#pragma unroll
    for (int i = 0; i < 3; i++) { accl[i] = z; accr[i] = z; }
    const bf16* hrow = h + (size_t)(row0 + l16) * 128 + quad * 8;
#pragma unroll
    for (int k0 = 0; k0 < 128; k0 += 32) {
        bf16x8 a = *reinterpret_cast<const bf16x8*>(hrow + k0);
        int cc = k0 * 2 + quad * 16;
        int sw = cc ^ ((l16 & 7) << 4);
#pragma unroll
        for (int ct = 0; ct < 3; ct++) {
            int rl = ct * 16 + l16;
            bf16x8 bl = *(const bf16x8*)(smem + rl * 256 + sw);
            bf16x8 br = *(const bf16x8*)(smem + 12288 + rl * 256 + sw);
            accl[ct] = __builtin_amdgcn_mfma_f32_16x16x32_bf16(a, bl, accl[ct], 0, 0, 0);
            accr[ct] = __builtin_amdgcn_mfma_f32_16x16x32_bf16(a, br, accr[ct], 0, 0, 0);
        }
    }
#pragma unroll
    for (int ct = 0; ct < 3; ct++)
#pragma unroll
        for (int r = 0; r < 4; r++) {
            size_t o = (size_t)(row0 + quad * 4 + r) * CLSP + ct * 16 + l16;
            outL[o] = __float2bfloat16(accl[ct][r]);
            outR[o] = __float2bfloat16(accr[ct][r]);
        }
}

// ---- K7: layer 2 fused. TWO nodes per wave (measured-best for l2), 8 lanes/edge.
// row64 removes the startA->csr chain here too.
struct L2S { float s; f32x2 acc[3]; };
__device__ __forceinline__ void l2_consume(U3 u, bool valid, const f32x2* xrp,
                                           const f32x2* a06, const float* a04, L2S& st) {
    f32x2 t0 = unpk2(u.x) + xrp[0];
    f32x2 t1 = unpk2(u.y) + xrp[1];
    f32x2 t2 = unpk2(u.z) + xrp[2];
    f32x2 ep = t0 * a06[0];
    ep = __builtin_elementwise_fma(t1, a06[1], ep);
    ep = __builtin_elementwise_fma(t2, a06[2], ep);
    float es = fmaf(a04[1], fabsf(t0.y), a04[0] * fabsf(t0.x));
    es = fmaf(a04[2], fabsf(t1.x), es);
    es = fmaf(a04[3], fabsf(t1.y), es);
    es = fmaf(a04[4], fabsf(t2.x), es);
    es = fmaf(a04[5], fabsf(t2.y), es);
    float e = (ep.x + ep.y) + es;
    e += __shfl_xor(e, 1);
    e += __shfl_xor(e, 2);
    e += __shfl_xor(e, 4);          // full 48-ch logit (8-lane group)
    float w = valid ? __builtin_amdgcn_exp2f(e) : 0.f;
    st.s += w;
    f32x2 wv = {w, w};
    st.acc[0] = __builtin_elementwise_fma(wv, t0, st.acc[0]);
    st.acc[1] = __builtin_elementwise_fma(wv, t1, st.acc[1]);
    st.acc[2] = __builtin_elementwise_fma(wv, t2, st.acc[2]);
}

__global__ __launch_bounds__(256) void node_l2(const int* __restrict__ startA,
                                               const int* __restrict__ degA,
                                               const int* __restrict__ csr_src,
                                               const int* __restrict__ row64,
                                               const bf16* __restrict__ xl2,
                                               const bf16* __restrict__ xr2,
                                               const float* __restrict__ a2,
                                               const float* __restrict__ b2,
                                               float* __restrict__ out) {
    int wv = (blockIdx.x * 256 + threadIdx.x) >> 6;
    int n0 = wv * 2, n1 = n0 + 1;
    int lane = threadIdx.x & 63;
    int g = lane >> 3, t = lane & 7;
    unsigned cB = (unsigned)t * 12;
    const char* xlb = (const char*)xl2;
    int c = t * 6;
    f32x2 a06[3];
    float a04[6], bv[6];
#pragma unroll
    for (int k = 0; k < 6; k++) {
        bool val = (c + k < CLS);
        float av = val ? a2[c + k] : 0.f;
        bv[k] = val ? b2[c + k] : 0.f;
        a04[k] = av * C04;
        if (k & 1) a06[k >> 1].y = av * C06; else a06[k >> 1].x = av * C06;
    }
    // independent startup loads for both nodes
    int dega = degA[n0], degb = degA[n1];
    unsigned rowBa = (unsigned)row64[(size_t)n0 * 64 + lane] * 96u;
    unsigned rowBb = (unsigned)row64[(size_t)n1 * 64 + lane] * 96u;
    f32x2 xra[3], xrb[3];
    {
        U3 ra = *(const U3*)((const char*)xr2 + (unsigned)n0 * 96u + cB);
        U3 rb = *(const U3*)((const char*)xr2 + (unsigned)n1 * 96u + cB);
        xra[0] = unpk2(ra.x); xra[1] = unpk2(ra.y); xra[2] = unpk2(ra.z);
        xrb[0] = unpk2(rb.x); xrb[1] = unpk2(rb.y); xrb[2] = unpk2(rb.z);
    }
    int nba = (dega + 7) >> 3, nbb = (degb + 7) >> 3;
    U3 ua[2], ub[2];
#pragma unroll
    for (int i = 0; i < 2; i++)
        ua[i] = *(const U3*)(xlb + (__shfl(rowBa, min(i * 8 + g, dega - 1)) + cB));
#pragma unroll
    for (int i = 0; i < 2; i++)
        ub[i] = *(const U3*)(xlb + (__shfl(rowBb, min(i * 8 + g, degb - 1)) + cB));
    L2S sa, sb;
    f32x2 z2 = {0.f, 0.f};
    sa.s = 0.f; sb.s = 0.f;
#pragma unroll
    for (int k = 0; k < 3; k++) { sa.acc[k] = z2; sb.acc[k] = z2; }
    // consume A round 1 (B's loads still in flight)
    l2_consume(ua[0], g < dega, xra, a06, a04, sa);
    if (nba > 1) l2_consume(ua[1], 8 + g < dega, xra, a06, a04, sa);
    U3 ua2[2];
    if (nba > 2) {
#pragma unroll
        for (int i = 0; i < 2; i++)
            ua2[i] = *(const U3*)(xlb + (__shfl(rowBa, min((i + 2) * 8 + g, dega - 1)) + cB));
    }
    // consume B round 1
    l2_consume(ub[0], g < degb, xrb, a06, a04, sb);
    if (nbb > 1) l2_consume(ub[1], 8 + g < degb, xrb, a06, a04, sb);
    U3 ub2[2];
    if (nbb > 2) {
#pragma unroll
        for (int i = 0; i < 2; i++)
            ub2[i] = *(const U3*)(xlb + (__shfl(rowBb, min((i + 2) * 8 + g, degb - 1)) + cB));
    }
    if (nba > 2) {
        l2_consume(ua2[0], 16 + g < dega, xra, a06, a04, sa);
        if (nba > 3) l2_consume(ua2[1], 24 + g < dega, xra, a06, a04, sa);
        if (nba > 4) {
            int j0a = (dega > 64) ? startA[n0] : 0;
            for (int b = 4; b < nba; b++) {
                int p = b * 8 + g;
                bool valid = p < dega;
                int pp = valid ? p : dega - 1;
                unsigned o = __shfl(rowBa, min(pp, 63)) + cB;
                if (pp >= 64) o = (unsigned)csr_src[j0a + pp] * 96u + cB;
                U3 uu = *(const U3*)(xlb + o);
                l2_consume(uu, valid, xra, a06, a04, sa);
            }
        }
    }
    if (nbb > 2) {
        l2_consume(ub2[0], 16 + g < degb, xrb, a06, a04, sb);
        if (nbb > 3) l2_consume(ub2[1], 24 + g < degb, xrb, a06, a04, sb);
        if (nbb > 4) {
            int j0b = (degb > 64) ? startA[n1] : 0;
            for (int b = 4; b < nbb; b++) {
                int p = b * 8 + g;
                bool valid = p < degb;
                int pp = valid ? p : degb - 1;
                unsigned o = __shfl(rowBb, min(pp, 63)) + cB;
                if (pp >= 64) o = (unsigned)csr_src[j0b + pp] * 96u + cB;
                U3 uu = *(const U3*)(xlb + o);
                l2_consume(uu, valid, xrb, a06, a04, sb);
            }
        }
    }
#pragma unroll
    for (int d = 8; d < 64; d <<= 1) {
        sa.s += __shfl_xor(sa.s, d);
        sb.s += __shfl_xor(sb.s, d);
#pragma unroll
        for (int k = 0; k < 3; k++) {
            sa.acc[k].x += __shfl_xor(sa.acc[k].x, d);
            sa.acc[k].y += __shfl_xor(sa.acc[k].y, d);
            sb.acc[k].x += __shfl_xor(sb.acc[k].x, d);
            sb.acc[k].y += __shfl_xor(sb.acc[k].y, d);
        }
    }
    // epilogue A
    {
        float inv = 1.f / sa.s;
        float q[6];
        float mx = -3e38f;
#pragma unroll
        for (int k = 0; k < 6; k++) {
            bool val = (c + k < CLS);
            float av = (k & 1) ? sa.acc[k >> 1].y : sa.acc[k >> 1].x;
            float xv = (k & 1) ? xra[k >> 1].y : xra[k >> 1].x;
            q[k] = val ? (av * inv - xv + bv[k]) : -3e38f;
            mx = fmaxf(mx, q[k]);
        }
        mx = fmaxf(mx, __shfl_xor(mx, 1));
        mx = fmaxf(mx, __shfl_xor(mx, 2));
        mx = fmaxf(mx, __shfl_xor(mx, 4));
        float se = 0.f;
#pragma unroll
        for (int k = 0; k < 6; k++) if (c + k < CLS) se += __expf(q[k] - mx);
        se += __shfl_xor(se, 1);
        se += __shfl_xor(se, 2);
        se += __shfl_xor(se, 4);
        float ls = mx + __logf(se);
        if (g == 0) {
            float* o = out + (size_t)n0 * CLS + c;
#pragma unroll
            for (int k = 0; k < 6; k++)
                if (c + k < CLS) o[k] = q[k] - ls;
        }
    }
    // epilogue B
    {
        float inv = 1.f / sb.s;
        float q[6];
        float mx = -3e38f;
#pragma unroll
        for (int k = 0; k < 6; k++) {
            bool val = (c + k < CLS);
            float av = (k & 1) ? sb.acc[k >> 1].y : sb.acc[k >> 1].x;
            float xv = (k & 1) ? xrb[k >> 1].y : xrb[k >> 1].x;
            q[k] = val ? (av * inv - xv + bv[k]) : -3e38f;
            mx = fmaxf(mx, q[k]);
        }
        mx = fmaxf(mx, __shfl_xor(mx, 1));
        mx = fmaxf(mx, __shfl_xor(mx, 2));
        mx = fmaxf(mx, __shfl_xor(mx, 4));
        float se = 0.f;
#pragma unroll
        for (int k = 0; k < 6; k++) if (c + k < CLS) se += __expf(q[k] - mx);
        se += __shfl_xor(se, 1);
        se += __shfl_xor(se, 2);
        se += __shfl_xor(se, 4);
        float ls = mx + __logf(se);
        if (g == 0) {
            float* o = out + (size_t)n1 * CLS + c;
#pragma unroll
            for (int k = 0; k < 6; k++)
                if (c + k < CLS) o[k] = q[k] - ls;
        }
    }
}

extern "C" void kernel_launch(void* const* d_in, const int* in_sizes, int n_in,
                              void* d_out, int out_size, void* d_ws, size_t ws_size,
                              hipStream_t stream) {
    const float* x   = (const float*)d_in[0];
    const int*   ei  = (const int*)d_in[1];
    const float* w1l = (const float*)d_in[2];
    const float* w1r = (const float*)d_in[3];
    const float* a1  = (const float*)d_in[4];
    const float* b1  = (const float*)d_in[5];
    const float* w2l = (const float*)d_in[6];
    const float* w2r = (const float*)d_in[7];
    const float* a2  = (const float*)d_in[8];
    const float* b2  = (const float*)d_in[9];
    float* out = (float*)d_out;

    // Workspace layout (total ~80.6 MB):
    char* base = (char*)d_ws;
    int*   bcursor = (int*)(base + 0);             //       784 B (zeroed by prep)
    int*   startA  = (int*)(base + 1024);          //   200,000 B
    int*   degA    = (int*)(base + 201024);        //   200,000 B
    uint2* tmp     = (uint2*)(base + 401024);      // 12,845,056 B (NBUCK*BCAP*8)
    int*   csr_src = (int*)(base + 13246080);      //  6,422,528 B (NBUCK*BCAP*4)
    bf16*  xl1     = (bf16*)(base + 19668608);     // 25,600,000 B (xl1|xr1)
    bf16*  hb      = (bf16*)(base + 45268608);     // 12,800,000 B
    bf16*  xl2p    = (bf16*)(base + 58068608);     //  9,600,000 B (xl2p|xr2p, stride 48)
    bf16*  wT1     = (bf16*)(base + 67668608);     //     65,536 B
    bf16*  wT2     = (bf16*)(base + 67734144);     //     24,576 B
    int*   row64   = (int*)(base + 67758720);      // 12,800,000 B (NN*64*4)
    bf16* xr1  = xl1 + (size_t)NN * 128;
    bf16* xr2p = xl2p + (size_t)NN * CLSP;

    prep<<<PREPB, 256, 0, stream>>>(w1l, w1r, w2l, w2r, wT1, wT2, bcursor);
    gemm1_scatter<<<GB1 + KAB, 256, 0, stream>>>(x, wT1, xl1, xr1, ei, bcursor, tmp);
    bucket_sort<<<NBUCK, 256, 0, stream>>>(bcursor, tmp, csr_src, startA, degA, row64);
    node_l1<<<(NN * 64) / 256, 256, 0, stream>>>(startA, degA, csr_src, row64, xl1, xr1, a1, b1, hb);
    gemm2<<<GB1, 256, 0, stream>>>(hb, wT2, xl2p, xr2p);
    node_l2<<<NODEB, 256, 0, stream>>>(startA, degA, csr_src, row64, xl2p, xr2p, a2, b2, out);
}

// Round 11
// 200.266 us; speedup vs baseline: 1.0161x; 1.0161x over previous
//
#include <hip/hip_runtime.h>
#include <hip/hip_bf16.h>
#include <math.h>

#define NN 50000
#define NE 800000
#define ETOT (NE + NN)      // 850000, self-loops appended after edges
#define CLS 40
#define CLSP 48             // layer-2 channels padded to 48
#define NEG 0.2f
#define MTILES (NN / 16)    // 3125 exact
#define GB1 ((MTILES + 3) / 4)   // 782 gemm blocks
#define PREPB 176           // prep blocks: ceil(45056/256)
#define NBUCK 196           // ceil(50000/256) dst buckets of 256 nodes
#define BCAP 8192           // per-bucket capacity (mean 4352, sd ~64)
#define EB 4096             // edges per scatter block
#define KAB ((ETOT + EB - 1) / EB)   // 208
#define NHALF (NN / 2)      // 25000: node_l1 split for profiling visibility
#define NODEB (NN / 8)      // 6250 blocks for node_l2: 4 waves/block, 2 nodes/wave

#define L2E 1.44269504088896f
#define C06 (0.6f * L2E)
#define C04 (0.4f * L2E)

typedef __hip_bfloat16 bf16;
typedef __attribute__((ext_vector_type(8))) __bf16 bf16x8;
typedef __attribute__((ext_vector_type(4))) float f32x4;
typedef __attribute__((ext_vector_type(2))) float f32x2;
struct U3 { unsigned x, y, z; };   // 12B, 4-aligned

__device__ __forceinline__ bf16x8 cvt8(f32x4 a, f32x4 b) {
    bf16x8 r;
    r[0] = (__bf16)a[0]; r[1] = (__bf16)a[1]; r[2] = (__bf16)a[2]; r[3] = (__bf16)a[3];
    r[4] = (__bf16)b[0]; r[5] = (__bf16)b[1]; r[6] = (__bf16)b[2]; r[7] = (__bf16)b[3];
    return r;
}
// 2 packed bf16 (one u32) -> f32x2 (register pair feeding v_pk_* ops)
__device__ __forceinline__ f32x2 unpk2(unsigned u) {
    f32x2 r;
    r.x = __uint_as_float(u << 16);
    r.y = __uint_as_float(u & 0xffff0000u);
    return r;
}

// 256-entry exclusive scan (4 waves). Returns exclusive prefix of v.
__device__ __forceinline__ unsigned scan256(unsigned v, unsigned* wsum) {
    int t = threadIdx.x;
    int lane = t & 63, w = t >> 6;
    unsigned inc = v;
#pragma unroll
    for (int d = 1; d < 64; d <<= 1) {
        unsigned x = __shfl_up(inc, d);
        if (lane >= d) inc += x;
    }
    if (lane == 63) wsum[w] = inc;
    __syncthreads();
    unsigned woff = 0;
#pragma unroll
    for (int i = 0; i < 4; i++) woff += (i < w) ? wsum[i] : 0;
    return woff + inc - v;
}

// ---- K1: weight prep (fp32->bf16 transposed) + zero bucket cursors. ----
__global__ __launch_bounds__(256) void prep(
        const float* __restrict__ w1l, const float* __restrict__ w1r,
        const float* __restrict__ w2l, const float* __restrict__ w2r,
        bf16* __restrict__ wT1, bf16* __restrict__ wT2,
        int* __restrict__ bcursor) {
    int t = blockIdx.x * 256 + threadIdx.x;
    if (t < NBUCK) bcursor[t] = 0;
    if (t < 2 * 128 * 128) {
        int m = t >> 14;
        int idx = t & 16383;
        int n = idx >> 7, k = idx & 127;
        const float* w = m ? w1r : w1l;
        wT1[t] = __float2bfloat16(w[k * 128 + n]);
    } else if (t < 2 * 128 * 128 + 2 * CLSP * 128) {
        int u = t - 2 * 128 * 128;
        int m = u / (CLSP * 128);
        int idx = u % (CLSP * 128);
        int n = idx >> 7, k = idx & 127;
        const float* w = m ? w2r : w2l;
        wT2[u] = __float2bfloat16((n < CLS) ? w[k * CLS + n] : 0.0f);
    }
}

// ---- K2: GEMM1 dual (LDS-staged weights) || LDS-binned edge scatter. ----
// One 64KB shared buffer, carved per branch. The gemm branch stages the full
// 2x128x128 bf16 weight table in LDS (XOR-swizzled, col ^= (row&7)<<4, applied
// on BOTH write and read) so the inner loop's weight reads are ds_read_b128
// instead of serialized L1/L2 round-trips (the measured 42us latency wall).
__global__ __launch_bounds__(256) void gemm1_scatter(
        const float* __restrict__ x, const bf16* __restrict__ wT,
        bf16* __restrict__ outL, bf16* __restrict__ outR,
        const int* __restrict__ ei, int* __restrict__ bcursor,
        uint2* __restrict__ tmp) {
    __shared__ __align__(16) char smem[65536];
    if ((int)blockIdx.x < GB1) {
        // ---- stage weights: 4096 x 16B chunks, swizzled ----
        const uint4* wsrc = (const uint4*)wT;
#pragma unroll
        for (int i = 0; i < 16; i++) {
            int idx = i * 256 + threadIdx.x;
            uint4 v = wsrc[idx];
            int r = idx >> 4;                  // 256B row
            int c = (idx & 15) << 4;           // byte col
            *(uint4*)(smem + r * 256 + (c ^ ((r & 7) << 4))) = v;
        }
        __syncthreads();
        int wave = threadIdx.x >> 6;
        int lane = threadIdx.x & 63;
        int tile = blockIdx.x * 4 + wave;
        if (tile >= MTILES) return;
        int row0 = tile * 16;
        int l16 = lane & 15, quad = lane >> 4;
        f32x4 z = {0.f, 0.f, 0.f, 0.f};
        f32x4 accl[8], accr[8];
#pragma unroll
        for (int i = 0; i < 8; i++) { accl[i] = z; accr[i] = z; }
        const float* xrow = x + (size_t)(row0 + l16) * 128 + quad * 8;
#pragma unroll
        for (int k0 = 0; k0 < 128; k0 += 32) {
            f32x4 a0 = *reinterpret_cast<const f32x4*>(xrow + k0);
            f32x4 a1v = *reinterpret_cast<const f32x4*>(xrow + k0 + 4);
            bf16x8 a = cvt8(a0, a1v);
            int cc = k0 * 2 + quad * 16;       // byte col of this lane's 16B
#pragma unroll
            for (int ct = 0; ct < 8; ct++) {
                int rl = ct * 16 + l16;        // wl row
                int sw = cc ^ ((l16 & 7) << 4);
                bf16x8 bl = *(const bf16x8*)(smem + rl * 256 + sw);
                bf16x8 br = *(const bf16x8*)(smem + 32768 + rl * 256 + sw);
                accl[ct] = __builtin_amdgcn_mfma_f32_16x16x32_bf16(a, bl, accl[ct], 0, 0, 0);
                accr[ct] = __builtin_amdgcn_mfma_f32_16x16x32_bf16(a, br, accr[ct], 0, 0, 0);
            }
        }
#pragma unroll
        for (int ct = 0; ct < 8; ct++)
#pragma unroll
            for (int r = 0; r < 4; r++) {
                size_t o = (size_t)(row0 + quad * 4 + r) * 128 + ct * 16 + l16;
                outL[o] = __float2bfloat16(accl[ct][r]);
                outR[o] = __float2bfloat16(accr[ct][r]);
            }
    } else {
        unsigned* hist   = (unsigned*)smem;                 // 1KB
        unsigned* lstart = (unsigned*)(smem + 1024);        // 1KB
        unsigned* lcur   = (unsigned*)(smem + 2048);        // 1KB
        unsigned* gbase  = (unsigned*)(smem + 3072);        // 1KB
        unsigned* wsum   = (unsigned*)(smem + 4096);        // 16B
        uint2*    binned = (uint2*)(smem + 4608);           // 32KB
        unsigned* target = (unsigned*)(smem + 37376);       // 16KB
        int t = threadIdx.x;
        int e0 = ((int)blockIdx.x - GB1) * EB;
        hist[t] = 0;
        __syncthreads();
        int srcs[16], dsts[16];
#pragma unroll
        for (int i = 0; i < 16; i++) {
            int e = e0 + i * 256 + t;
            if (e < ETOT) {
                int s, d;
                if (e < NE) { s = ei[e]; d = ei[NE + e]; }
                else        { s = d = e - NE; }
                srcs[i] = s; dsts[i] = d;
                atomicAdd(&hist[d >> 8], 1u);
            } else dsts[i] = -1;
        }
        __syncthreads();
        unsigned v = hist[t];
        unsigned excl = scan256(v, wsum);
        lstart[t] = excl;
        lcur[t] = 0;
        __syncthreads();
        if (t < NBUCK && v > 0)
            gbase[t] = (unsigned)atomicAdd(&bcursor[t], (int)v) + (unsigned)t * BCAP;
        __syncthreads();
#pragma unroll
        for (int i = 0; i < 16; i++) {
            int d = dsts[i];
            if (d >= 0) {
                int bk = d >> 8;
                unsigned p = atomicAdd(&lcur[bk], 1u);
                unsigned slot = lstart[bk] + p;
                binned[slot] = make_uint2((unsigned)srcs[i], (unsigned)d);
                target[slot] = gbase[bk] + p;
            }
        }
        __syncthreads();
        int tot = min(EB, ETOT - e0);
        for (int s = t; s < tot; s += 256)
            tmp[target[s]] = binned[s];
    }
}

// ---- KB: per-bucket node sort -> csr_src + start/deg + padded row32. ----
// Scattered permutation stays in LDS; all global writes are coalesced streams.
// row32[node][slot] = csr[start+min(slot,deg-1)] pre-clamps the first 32
// sources per node (the node kernels' main paths only ever shuffle entries
// 0..31) so their startup loads are all INDEPENDENT (no startA->csr chain).
// deg>32 tail reads csr_src directly (rare, wave-uniform branch).
__global__ __launch_bounds__(256) void bucket_sort(const int* __restrict__ bcursor,
                                                   const uint2* __restrict__ tmp,
                                                   int* __restrict__ csr_src,
                                                   int* __restrict__ startA,
                                                   int* __restrict__ degA,
                                                   int* __restrict__ row32) {
    __shared__ unsigned hist[256];
    __shared__ unsigned lstart[256];
    __shared__ unsigned lcur[256];
    __shared__ unsigned wsum[4];
    __shared__ int vals[BCAP];          // 32 KB LDS staging
    int b = blockIdx.x, t = threadIdx.x;
    int cnt = bcursor[b];
    hist[t] = 0;
    __syncthreads();
    const uint2* seg = tmp + (size_t)b * BCAP;
    for (int s = t; s < cnt; s += 256)
        atomicAdd(&hist[seg[s].y & 255], 1u);
    __syncthreads();
    unsigned v = hist[t];
    unsigned excl = scan256(v, wsum);
    lstart[t] = excl;
    lcur[t] = excl;
    int node = b * 256 + t;
    if (node < NN) {
        startA[node] = b * BCAP + (int)excl;
        degA[node] = (int)v;
    }
    __syncthreads();
    for (int s = t; s < cnt; s += 256) {
        uint2 p = seg[s];                       // L2-hot re-read
        unsigned pos = atomicAdd(&lcur[p.y & 255], 1u);
        vals[pos] = (int)p.x;                   // scattered write stays in LDS
    }
    __syncthreads();
    int* cbase = csr_src + (size_t)b * BCAP;
    for (int s = t; s < cnt; s += 256)
        cbase[s] = vals[s];                     // coalesced global stream
    // padded first-32 adjacency: 8 nodes per iteration (32 lanes each);
    // iteration i writes nodes [i*8, i*8+8) -> 1KB contiguous global store;
    // LDS reads are consecutive (conflict-free).
    int slot = t & 31;
#pragma unroll 4
    for (int i = 0; i < 32; i++) {
        int n2 = (t >> 5) + i * 8;
        int node2 = b * 256 + n2;
        if (node2 < NN) {
            int d2 = (int)hist[n2];
            int e2 = (int)lstart[n2];
            row32[(size_t)node2 * 32 + slot] = vals[e2 + min(slot, d2 - 1)];
        }
    }
}

// ---- K5: layer 1 fused. ONE node/wave, 16 lanes/edge, up to 32 edges in
// flight. Startup loads {deg, row32, xr} are all independent. Split into two
// half dispatches (nbase) for profiling visibility; halves are independent.
struct L1S { float s; f32x2 acc[4]; };
__device__ __forceinline__ void l1_consume(uint4 u, bool valid, const f32x2* xrp,
                                           const f32x2* a06, const float* a04, L1S& st) {
    f32x2 t0 = unpk2(u.x) + xrp[0];
    f32x2 t1 = unpk2(u.y) + xrp[1];
    f32x2 t2 = unpk2(u.z) + xrp[2];
    f32x2 t3 = unpk2(u.w) + xrp[3];
    f32x2 ep = t0 * a06[0];
    ep = __builtin_elementwise_fma(t1, a06[1], ep);
    ep = __builtin_elementwise_fma(t2, a06[2], ep);
    ep = __builtin_elementwise_fma(t3, a06[3], ep);
    float e0 = fmaf(a04[1], fabsf(t0.y), a04[0] * fabsf(t0.x));
    e0 = fmaf(a04[2], fabsf(t1.x), e0);
    e0 = fmaf(a04[3], fabsf(t1.y), e0);
    float e1 = fmaf(a04[5], fabsf(t2.y), a04[4] * fabsf(t2.x));
    e1 = fmaf(a04[6], fabsf(t3.x), e1);
    e1 = fmaf(a04[7], fabsf(t3.y), e1);
    float e = (ep.x + ep.y) + (e0 + e1);
    e += __shfl_xor(e, 1);
    e += __shfl_xor(e, 2);          // per-head logit (4-lane quad)
    float w = valid ? __builtin_amdgcn_exp2f(e) : 0.f;
    st.s += w;
    f32x2 wv = {w, w};
    st.acc[0] = __builtin_elementwise_fma(wv, t0, st.acc[0]);
    st.acc[1] = __builtin_elementwise_fma(wv, t1, st.acc[1]);
    st.acc[2] = __builtin_elementwise_fma(wv, t2, st.acc[2]);
    st.acc[3] = __builtin_elementwise_fma(wv, t3, st.acc[3]);
}

__global__ __launch_bounds__(256) void node_l1(const int* __restrict__ startA,
                                               const int* __restrict__ degA,
                                               const int* __restrict__ csr_src,
                                               const int* __restrict__ row32,
                                               const bf16* __restrict__ xl,
                                               const bf16* __restrict__ xr,
                                               const float* __restrict__ a1,
                                               const float* __restrict__ b1,
                                               bf16* __restrict__ hb,
                                               int nbase) {
    int wid = nbase + ((blockIdx.x * 256 + threadIdx.x) >> 6);
    int lane = threadIdx.x & 63;
    int g = lane >> 4, t = lane & 15;
    unsigned cB = (unsigned)t * 16;
    // three INDEPENDENT startup loads (no dependent chain)
    int deg = degA[wid];
    unsigned rowB = (unsigned)row32[((size_t)wid << 5) + (lane & 31)] << 8;
    const char* xlb = (const char*)xl;
    f32x2 xrp[4];
    {
        uint4 raw = *(const uint4*)((const char*)xr + ((unsigned)wid << 8) + cB);
        xrp[0] = unpk2(raw.x); xrp[1] = unpk2(raw.y);
        xrp[2] = unpk2(raw.z); xrp[3] = unpk2(raw.w);
    }
    f32x2 a06[4];
    float a04[8];
    {
        f32x4 lo = *reinterpret_cast<const f32x4*>(a1 + t * 8);
        f32x4 hi = *reinterpret_cast<const f32x4*>(a1 + t * 8 + 4);
        float af[8];
#pragma unroll
        for (int k = 0; k < 4; k++) { af[k] = lo[k]; af[k + 4] = hi[k]; }
#pragma unroll
        for (int j = 0; j < 4; j++) {
            a06[j].x = af[2 * j] * C06;
            a06[j].y = af[2 * j + 1] * C06;
        }
#pragma unroll
        for (int k = 0; k < 8; k++) a04[k] = af[k] * C04;
    }
    L1S st; st.s = 0.f;
    f32x2 z2 = {0.f, 0.f};
#pragma unroll
    for (int k = 0; k < 4; k++) st.acc[k] = z2;
    int nb = (deg + 3) >> 2;      // 4 edges per batch, one per 16-lane group
    uint4 u[8];
#pragma unroll
    for (int i = 0; i < 4; i++) {
        int pp = min(i * 4 + g, deg - 1);     // <= 31, shfl-safe
        u[i] = *(const uint4*)(xlb + (__shfl(rowB, pp) + cB));
    }
    if (nb > 4) {
#pragma unroll
        for (int i = 4; i < 8; i++) {
            int pp = min(i * 4 + g, deg - 1); // <= 31, shfl-safe
            u[i] = *(const uint4*)(xlb + (__shfl(rowB, pp) + cB));
        }
    }
    l1_consume(u[0], g < deg, xrp, a06, a04, st);
    if (nb > 1) l1_consume(u[1], 4 + g < deg, xrp, a06, a04, st);
    if (nb > 2) l1_consume(u[2], 8 + g < deg, xrp, a06, a04, st);
    if (nb > 3) l1_consume(u[3], 12 + g < deg, xrp, a06, a04, st);
    if (nb > 4) {
        l1_consume(u[4], 16 + g < deg, xrp, a06, a04, st);
        if (nb > 5) l1_consume(u[5], 20 + g < deg, xrp, a06, a04, st);
        if (nb > 6) l1_consume(u[6], 24 + g < deg, xrp, a06, a04, st);
        if (nb > 7) l1_consume(u[7], 28 + g < deg, xrp, a06, a04, st);
        if (nb > 8) {
            // deg > 32: rare serial fallback reads csr directly (pp >= 32).
            int j0t = startA[wid];
            for (int b = 8; b < nb; b++) {
                int p = b * 4 + g;
                bool valid = p < deg;
                int pp = valid ? p : deg - 1;       // >= 32 since deg > 32
                unsigned o = (((unsigned)csr_src[j0t + pp]) << 8) + cB;
                uint4 uu = *(const uint4*)(xlb + o);
                l1_consume(uu, valid, xrp, a06, a04, st);
            }
        }
    }
#pragma unroll
    for (int d = 16; d < 64; d <<= 1) {
        st.s += __shfl_xor(st.s, d);
#pragma unroll
        for (int k = 0; k < 4; k++) {
            st.acc[k].x += __shfl_xor(st.acc[k].x, d);
            st.acc[k].y += __shfl_xor(st.acc[k].y, d);
        }
    }
    if (g == 0) {
        float inv = 1.f / st.s;
        unsigned pk[4];
#pragma unroll
        for (int k = 0; k < 4; k++) {
            float o0 = st.acc[k].x * inv - xrp[k].x + b1[t * 8 + 2 * k];
            float o1 = st.acc[k].y * inv - xrp[k].y + b1[t * 8 + 2 * k + 1];
            o0 = o0 > 0.f ? o0 : __expf(o0) - 1.f;
            o1 = o1 > 0.f ? o1 : __expf(o1) - 1.f;
            bf16 r0 = __float2bfloat16(o0), r1 = __float2bfloat16(o1);
            pk[k] = (unsigned)*reinterpret_cast<unsigned short*>(&r0) |
                    ((unsigned)*reinterpret_cast<unsigned short*>(&r1) << 16);
        }
        uint4 w4 = {pk[0], pk[1], pk[2], pk[3]};
        *(uint4*)((char*)hb + ((unsigned)wid << 8) + cB) = w4;
    }
}

// ---- K6: GEMM2 dual (LDS-staged 24KB weights, same swizzle scheme). ----
__global__ __launch_bounds__(256) void gemm2(const bf16* __restrict__ h,
                                             const bf16* __restrict__ wT,
                                             bf16* __restrict__ outL,
                                             bf16* __restrict__ outR) {
    __shared__ __align__(16) char smem[24576];   // 96 rows x 256B
    const uint4* wsrc = (const uint4*)wT;
#pragma unroll
    for (int i = 0; i < 6; i++) {
        int idx = i * 256 + threadIdx.x;
        uint4 v = wsrc[idx];
        int r = idx >> 4;
        int c = (idx & 15) << 4;
        *(uint4*)(smem + r * 256 + (c ^ ((r & 7) << 4))) = v;
    }
    __syncthreads();
    int wave = threadIdx.x >> 6;
    int lane = threadIdx.x & 63;
    int tile = blockIdx.x * 4 + wave;
    if (tile >= MTILES) return;
    int row0 = tile * 16;
    int l16 = lane & 15, quad = lane >> 4;
    f32x4 z = {0.f, 0.f, 0.f, 0.f};
    f32x4 accl[3], accr[3];
#pragma unroll
    for (int i = 0; i < 3; i++) { accl[i] = z; accr[i] = z; }
    const bf16* hrow = h + (size_t)(row0 + l16) * 128 + quad * 8;
#pragma unroll
    for (int k0 = 0; k0 < 128; k0 += 32) {
        bf16x8 a = *reinterpret_cast<const bf16x8*>(hrow + k0);
        int cc = k0 * 2 + quad * 16;
        int sw = cc ^ ((l16 & 7) << 4);
#pragma unroll
        for (int ct = 0; ct < 3; ct++) {
            int rl = ct * 16 + l16;
            bf16x8 bl = *(const bf16x8*)(smem + rl * 256 + sw);
            bf16x8 br = *(const bf16x8*)(smem + 12288 + rl * 256 + sw);
            accl[ct] = __builtin_amdgcn_mfma_f32_16x16x32_bf16(a, bl, accl[ct], 0, 0, 0);
            accr[ct] = __builtin_amdgcn_mfma_f32_16x16x32_bf16(a, br, accr[ct], 0, 0, 0);
        }
    }
#pragma unroll
    for (int ct = 0; ct < 3; ct++)
#pragma unroll
        for (int r = 0; r < 4; r++) {
            size_t o = (size_t)(row0 + quad * 4 + r) * CLSP + ct * 16 + l16;
            outL[o] = __float2bfloat16(accl[ct][r]);
            outR[o] = __float2bfloat16(accr[ct][r]);
        }
}

// ---- K7: layer 2 fused. TWO nodes per wave (measured-best for l2), 8 lanes/edge.
// row32 removes the startA->csr chain here too.
struct L2S { float s; f32x2 acc[3]; };
__device__ __forceinline__ void l2_consume(U3 u, bool valid, const f32x2* xrp,
                                           const f32x2* a06, const float* a04, L2S& st) {
    f32x2 t0 = unpk2(u.x) + xrp[0];
    f32x2 t1 = unpk2(u.y) + xrp[1];
    f32x2 t2 = unpk2(u.z) + xrp[2];
    f32x2 ep = t0 * a06[0];
    ep = __builtin_elementwise_fma(t1, a06[1], ep);
    ep = __builtin_elementwise_fma(t2, a06[2], ep);
    float es = fmaf(a04[1], fabsf(t0.y), a04[0] * fabsf(t0.x));
    es = fmaf(a04[2], fabsf(t1.x), es);
    es = fmaf(a04[3], fabsf(t1.y), es);
    es = fmaf(a04[4], fabsf(t2.x), es);
    es = fmaf(a04[5], fabsf(t2.y), es);
    float e = (ep.x + ep.y) + es;
    e += __shfl_xor(e, 1);
    e += __shfl_xor(e, 2);
    e += __shfl_xor(e, 4);          // full 48-ch logit (8-lane group)
    float w = valid ? __builtin_amdgcn_exp2f(e) : 0.f;
    st.s += w;
    f32x2 wv = {w, w};
    st.acc[0] = __builtin_elementwise_fma(wv, t0, st.acc[0]);
    st.acc[1] = __builtin_elementwise_fma(wv, t1, st.acc[1]);
    st.acc[2] = __builtin_elementwise_fma(wv, t2, st.acc[2]);
}

__global__ __launch_bounds__(256) void node_l2(const int* __restrict__ startA,
                                               const int* __restrict__ degA,
                                               const int* __restrict__ csr_src,
                                               const int* __restrict__ row32,
                                               const bf16* __restrict__ xl2,
                                               const bf16* __restrict__ xr2,
                                               const float* __restrict__ a2,
                                               const float* __restrict__ b2,
                                               float* __restrict__ out) {
    int wv = (blockIdx.x * 256 + threadIdx.x) >> 6;
    int n0 = wv * 2, n1 = n0 + 1;
    int lane = threadIdx.x & 63;
    int g = lane >> 3, t = lane & 7;
    unsigned cB = (unsigned)t * 12;
    const char* xlb = (const char*)xl2;
    int c = t * 6;
    f32x2 a06[3];
    float a04[6], bv[6];
#pragma unroll
    for (int k = 0; k < 6; k++) {
        bool val = (c + k < CLS);
        float av = val ? a2[c + k] : 0.f;
        bv[k] = val ? b2[c + k] : 0.f;
        a04[k] = av * C04;
        if (k & 1) a06[k >> 1].y = av * C06; else a06[k >> 1].x = av * C06;
    }
    // independent startup loads for both nodes
    int dega = degA[n0], degb = degA[n1];
    unsigned rowBa = (unsigned)row32[((size_t)n0 << 5) + (lane & 31)] * 96u;
    unsigned rowBb = (unsigned)row32[((size_t)n1 << 5) + (lane & 31)] * 96u;
    f32x2 xra[3], xrb[3];
    {
        U3 ra = *(const U3*)((const char*)xr2 + (unsigned)n0 * 96u + cB);
        U3 rb = *(const U3*)((const char*)xr2 + (unsigned)n1 * 96u + cB);
        xra[0] = unpk2(ra.x); xra[1] = unpk2(ra.y); xra[2] = unpk2(ra.z);
        xrb[0] = unpk2(rb.x); xrb[1] = unpk2(rb.y); xrb[2] = unpk2(rb.z);
    }
    int nba = (dega + 7) >> 3, nbb = (degb + 7) >> 3;
    U3 ua[2], ub[2];
#pragma unroll
    for (int i = 0; i < 2; i++)
        ua[i] = *(const U3*)(xlb + (__shfl(rowBa, min(i * 8 + g, dega - 1)) + cB));
#pragma unroll
    for (int i = 0; i < 2; i++)
        ub[i] = *(const U3*)(xlb + (__shfl(rowBb, min(i * 8 + g, degb - 1)) + cB));
    L2S sa, sb;
    f32x2 z2 = {0.f, 0.f};
    sa.s = 0.f; sb.s = 0.f;
#pragma unroll
    for (int k = 0; k < 3; k++) { sa.acc[k] = z2; sb.acc[k] = z2; }
    // consume A round 1 (B's loads still in flight)
    l2_consume(ua[0], g < dega, xra, a06, a04, sa);
    if (nba > 1) l2_consume(ua[1], 8 + g < dega, xra, a06, a04, sa);
    U3 ua2[2];
    if (nba > 2) {
#pragma unroll
        for (int i = 0; i < 2; i++)
            ua2[i] = *(const U3*)(xlb + (__shfl(rowBa, min((i + 2) * 8 + g, dega - 1)) + cB));
    }
    // consume B round 1
    l2_consume(ub[0], g < degb, xrb, a06, a04, sb);
    if (nbb > 1) l2_consume(ub[1], 8 + g < degb, xrb, a06, a04, sb);
    U3 ub2[2];
    if (nbb > 2) {
#pragma unroll
        for (int i = 0; i < 2; i++)
            ub2[i] = *(const U3*)(xlb + (__shfl(rowBb, min((i + 2) * 8 + g, degb - 1)) + cB));
    }
    if (nba > 2) {
        l2_consume(ua2[0], 16 + g < dega, xra, a06, a04, sa);
        if (nba > 3) l2_consume(ua2[1], 24 + g < dega, xra, a06, a04, sa);
        if (nba > 4) {
            // deg > 32: rare serial fallback reads csr directly (pp >= 32).
            int j0a = startA[n0];
            for (int b = 4; b < nba; b++) {
                int p = b * 8 + g;
                bool valid = p < dega;
                int pp = valid ? p : dega - 1;      // >= 32 since dega > 32
                unsigned o = (unsigned)csr_src[j0a + pp] * 96u + cB;
                U3 uu = *(const U3*)(xlb + o);
                l2_consume(uu, valid, xra, a06, a04, sa);
            }
        }
    }
    if (nbb > 2) {
        l2_consume(ub2[0], 16 + g < degb, xrb, a06, a04, sb);
        if (nbb > 3) l2_consume(ub2[1], 24 + g < degb, xrb, a06, a04, sb);
        if (nbb > 4) {
            int j0b = startA[n1];
            for (int b = 4; b < nbb; b++) {
                int p = b * 8 + g;
                bool valid = p < degb;
                int pp = valid ? p : degb - 1;      // >= 32 since degb > 32
                unsigned o = (unsigned)csr_src[j0b + pp] * 96u + cB;
                U3 uu = *(const U3*)(xlb + o);
                l2_consume(uu, valid, xrb, a06, a04, sb);
            }
        }
    }
#pragma unroll
    for (int d = 8; d < 64; d <<= 1) {
        sa.s += __shfl_xor(sa.s, d);
        sb.s += __shfl_xor(sb.s, d);
#pragma unroll
        for (int k = 0; k < 3; k++) {
            sa.acc[k].x += __shfl_xor(sa.acc[k].x, d);
            sa.acc[k].y += __shfl_xor(sa.acc[k].y, d);
            sb.acc[k].x += __shfl_xor(sb.acc[k].x, d);
            sb.acc[k].y += __shfl_xor(sb.acc[k].y, d);
        }
    }
    // epilogue A
    {
        float inv = 1.f / sa.s;
        float q[6];
        float mx = -3e38f;
#pragma unroll
        for (int k = 0; k < 6; k++) {
            bool val = (c + k < CLS);
            float av = (k & 1) ? sa.acc[k >> 1].y : sa.acc[k >> 1].x;
            float xv = (k & 1) ? xra[k >> 1].y : xra[k >> 1].x;
            q[k] = val ? (av * inv - xv + bv[k]) : -3e38f;
            mx = fmaxf(mx, q[k]);
        }
        mx = fmaxf(mx, __shfl_xor(mx, 1));
        mx = fmaxf(mx, __shfl_xor(mx, 2));
        mx = fmaxf(mx, __shfl_xor(mx, 4));
        float se = 0.f;
#pragma unroll
        for (int k = 0; k < 6; k++) if (c + k < CLS) se += __expf(q[k] - mx);
        se += __shfl_xor(se, 1);
        se += __shfl_xor(se, 2);
        se += __shfl_xor(se, 4);
        float ls = mx + __logf(se);
        if (g == 0) {
            float* o = out + (size_t)n0 * CLS + c;
#pragma unroll
            for (int k = 0; k < 6; k++)
                if (c + k < CLS) o[k] = q[k] - ls;
        }
    }
    // epilogue B
    {
        float inv = 1.f / sb.s;
        float q[6];
        float mx = -3e38f;
#pragma unroll
        for (int k = 0; k < 6; k++) {
            bool val = (c + k < CLS);
            float av = (k & 1) ? sb.acc[k >> 1].y : sb.acc[k >> 1].x;
            float xv = (k & 1) ? xrb[k >> 1].y : xrb[k >> 1].x;
            q[k] = val ? (av * inv - xv + bv[k]) : -3e38f;
            mx = fmaxf(mx, q[k]);
        }
        mx = fmaxf(mx, __shfl_xor(mx, 1));
        mx = fmaxf(mx, __shfl_xor(mx, 2));
        mx = fmaxf(mx, __shfl_xor(mx, 4));
        float se = 0.f;
#pragma unroll
        for (int k = 0; k < 6; k++) if (c + k < CLS) se += __expf(q[k] - mx);
        se += __shfl_xor(se, 1);
        se += __shfl_xor(se, 2);
        se += __shfl_xor(se, 4);
        float ls = mx + __logf(se);
        if (g == 0) {
            float* o = out + (size_t)n1 * CLS + c;
#pragma unroll
            for (int k = 0; k < 6; k++)
                if (c + k < CLS) o[k] = q[k] - ls;
        }
    }
}

extern "C" void kernel_launch(void* const* d_in, const int* in_sizes, int n_in,
                              void* d_out, int out_size, void* d_ws, size_t ws_size,
                              hipStream_t stream) {
    const float* x   = (const float*)d_in[0];
    const int*   ei  = (const int*)d_in[1];
    const float* w1l = (const float*)d_in[2];
    const float* w1r = (const float*)d_in[3];
    const float* a1  = (const float*)d_in[4];
    const float* b1  = (const float*)d_in[5];
    const float* w2l = (const float*)d_in[6];
    const float* w2r = (const float*)d_in[7];
    const float* a2  = (const float*)d_in[8];
    const float* b2  = (const float*)d_in[9];
    float* out = (float*)d_out;

    // Workspace layout (total ~74.2 MB):
    char* base = (char*)d_ws;
    int*   bcursor = (int*)(base + 0);             //       784 B (zeroed by prep)
    int*   startA  = (int*)(base + 1024);          //   200,000 B
    int*   degA    = (int*)(base + 201024);        //   200,000 B
    uint2* tmp     = (uint2*)(base + 401024);      // 12,845,056 B (NBUCK*BCAP*8)
    int*   csr_src = (int*)(base + 13246080);      //  6,422,528 B (NBUCK*BCAP*4)
    bf16*  xl1     = (bf16*)(base + 19668608);     // 25,600,000 B (xl1|xr1)
    bf16*  hb      = (bf16*)(base + 45268608);     // 12,800,000 B
    bf16*  xl2p    = (bf16*)(base + 58068608);     //  9,600,000 B (xl2p|xr2p, stride 48)
    bf16*  wT1     = (bf16*)(base + 67668608);     //     65,536 B
    bf16*  wT2     = (bf16*)(base + 67734144);     //     24,576 B
    int*   row32   = (int*)(base + 67758720);      //  6,400,000 B (NN*32*4)
    bf16* xr1  = xl1 + (size_t)NN * 128;
    bf16* xr2p = xl2p + (size_t)NN * CLSP;

    prep<<<PREPB, 256, 0, stream>>>(w1l, w1r, w2l, w2r, wT1, wT2, bcursor);
    gemm1_scatter<<<GB1 + KAB, 256, 0, stream>>>(x, wT1, xl1, xr1, ei, bcursor, tmp);
    bucket_sort<<<NBUCK, 256, 0, stream>>>(bcursor, tmp, csr_src, startA, degA, row32);
    node_l1<<<(NHALF * 64) / 256, 256, 0, stream>>>(startA, degA, csr_src, row32, xl1, xr1, a1, b1, hb, 0);
    node_l1<<<(NHALF * 64) / 256, 256, 0, stream>>>(startA, degA, csr_src, row32, xl1, xr1, a1, b1, hb, NHALF);
    gemm2<<<GB1, 256, 0, stream>>>(hb, wT2, xl2p, xr2p);
    node_l2<<<NODEB, 256, 0, stream>>>(startA, degA, csr_src, row32, xl2p, xr2p, a2, b2, out);
}

// Round 12
// 195.690 us; speedup vs baseline: 1.0399x; 1.0234x over previous
//
#include <hip/hip_runtime.h>
#include <hip/hip_bf16.h>
#include <math.h>

#define NN 50000
#define NE 800000
#define ETOT (NE + NN)      // 850000, self-loops appended after edges
#define CLS 40
#define CLSP 48             // layer-2 channels padded to 48
#define NEG 0.2f
#define MTILES (NN / 16)    // 3125 exact
#define GB1 ((MTILES + 3) / 4)   // 782 gemm blocks
#define PREPB 176           // prep blocks: ceil(45056/256)
#define NBUCK 196           // ceil(50000/256) dst buckets of 256 nodes
#define BCAP 8192           // per-bucket capacity (mean 4352, sd ~64)
#define EB 4096             // edges per scatter block
#define KAB ((ETOT + EB - 1) / EB)   // 208
#define NODEB (NN / 8)      // 6250 blocks for node_l2: 4 waves/block, 2 nodes/wave

#define L2E 1.44269504088896f
#define C06 (0.6f * L2E)
#define C04 (0.4f * L2E)

typedef __hip_bfloat16 bf16;
typedef __attribute__((ext_vector_type(8))) __bf16 bf16x8;
typedef __attribute__((ext_vector_type(4))) float f32x4;
typedef __attribute__((ext_vector_type(2))) float f32x2;
struct U3 { unsigned x, y, z; };   // 12B, 4-aligned

__device__ __forceinline__ bf16x8 cvt8(f32x4 a, f32x4 b) {
    bf16x8 r;
    r[0] = (__bf16)a[0]; r[1] = (__bf16)a[1]; r[2] = (__bf16)a[2]; r[3] = (__bf16)a[3];
    r[4] = (__bf16)b[0]; r[5] = (__bf16)b[1]; r[6] = (__bf16)b[2]; r[7] = (__bf16)b[3];
    return r;
}
// 2 packed bf16 (one u32) -> f32x2 (register pair feeding v_pk_* ops)
__device__ __forceinline__ f32x2 unpk2(unsigned u) {
    f32x2 r;
    r.x = __uint_as_float(u << 16);
    r.y = __uint_as_float(u & 0xffff0000u);
    return r;
}

// 256-entry exclusive scan (4 waves). Returns exclusive prefix of v.
__device__ __forceinline__ unsigned scan256(unsigned v, unsigned* wsum) {
    int t = threadIdx.x;
    int lane = t & 63, w = t >> 6;
    unsigned inc = v;
#pragma unroll
    for (int d = 1; d < 64; d <<= 1) {
        unsigned x = __shfl_up(inc, d);
        if (lane >= d) inc += x;
    }
    if (lane == 63) wsum[w] = inc;
    __syncthreads();
    unsigned woff = 0;
#pragma unroll
    for (int i = 0; i < 4; i++) woff += (i < w) ? wsum[i] : 0;
    return woff + inc - v;
}

// ---- K1: weight prep (fp32->bf16 transposed) + zero bucket cursors. ----
__global__ __launch_bounds__(256) void prep(
        const float* __restrict__ w1l, const float* __restrict__ w1r,
        const float* __restrict__ w2l, const float* __restrict__ w2r,
        bf16* __restrict__ wT1, bf16* __restrict__ wT2,
        int* __restrict__ bcursor) {
    int t = blockIdx.x * 256 + threadIdx.x;
    if (t < NBUCK) bcursor[t] = 0;
    if (t < 2 * 128 * 128) {
        int m = t >> 14;
        int idx = t & 16383;
        int n = idx >> 7, k = idx & 127;
        const float* w = m ? w1r : w1l;
        wT1[t] = __float2bfloat16(w[k * 128 + n]);
    } else if (t < 2 * 128 * 128 + 2 * CLSP * 128) {
        int u = t - 2 * 128 * 128;
        int m = u / (CLSP * 128);
        int idx = u % (CLSP * 128);
        int n = idx >> 7, k = idx & 127;
        const float* w = m ? w2r : w2l;
        wT2[u] = __float2bfloat16((n < CLS) ? w[k * CLS + n] : 0.0f);
    }
}

// ---- K2: GEMM1 dual (LDS-staged weights) || LDS-binned edge scatter. ----
// One 64KB shared buffer, carved per branch. The gemm branch stages the full
// 2x128x128 bf16 weight table in LDS (XOR-swizzled, col ^= (row&7)<<4, applied
// on BOTH write and read) so the inner loop's weight reads are ds_read_b128
// instead of serialized L1/L2 round-trips (the measured 42us latency wall).
// Scatter branch packs each edge record into 32 bits: (src<<8)|(dst&255) —
// src < 50000 fits 16 bits, and downstream only needs dst's low 8 bits
// (the within-bucket node id). Halves tmp traffic + binned LDS.
__global__ __launch_bounds__(256) void gemm1_scatter(
        const float* __restrict__ x, const bf16* __restrict__ wT,
        bf16* __restrict__ outL, bf16* __restrict__ outR,
        const int* __restrict__ ei, int* __restrict__ bcursor,
        unsigned* __restrict__ tmp) {
    __shared__ __align__(16) char smem[65536];
    if ((int)blockIdx.x < GB1) {
        // ---- stage weights: 4096 x 16B chunks, swizzled ----
        const uint4* wsrc = (const uint4*)wT;
#pragma unroll
        for (int i = 0; i < 16; i++) {
            int idx = i * 256 + threadIdx.x;
            uint4 v = wsrc[idx];
            int r = idx >> 4;                  // 256B row
            int c = (idx & 15) << 4;           // byte col
            *(uint4*)(smem + r * 256 + (c ^ ((r & 7) << 4))) = v;
        }
        __syncthreads();
        int wave = threadIdx.x >> 6;
        int lane = threadIdx.x & 63;
        int tile = blockIdx.x * 4 + wave;
        if (tile >= MTILES) return;
        int row0 = tile * 16;
        int l16 = lane & 15, quad = lane >> 4;
        f32x4 z = {0.f, 0.f, 0.f, 0.f};
        f32x4 accl[8], accr[8];
#pragma unroll
        for (int i = 0; i < 8; i++) { accl[i] = z; accr[i] = z; }
        const float* xrow = x + (size_t)(row0 + l16) * 128 + quad * 8;
#pragma unroll
        for (int k0 = 0; k0 < 128; k0 += 32) {
            f32x4 a0 = *reinterpret_cast<const f32x4*>(xrow + k0);
            f32x4 a1v = *reinterpret_cast<const f32x4*>(xrow + k0 + 4);
            bf16x8 a = cvt8(a0, a1v);
            int cc = k0 * 2 + quad * 16;       // byte col of this lane's 16B
#pragma unroll
            for (int ct = 0; ct < 8; ct++) {
                int rl = ct * 16 + l16;        // wl row
                int sw = cc ^ ((l16 & 7) << 4);
                bf16x8 bl = *(const bf16x8*)(smem + rl * 256 + sw);
                bf16x8 br = *(const bf16x8*)(smem + 32768 + rl * 256 + sw);
                accl[ct] = __builtin_amdgcn_mfma_f32_16x16x32_bf16(a, bl, accl[ct], 0, 0, 0);
                accr[ct] = __builtin_amdgcn_mfma_f32_16x16x32_bf16(a, br, accr[ct], 0, 0, 0);
            }
        }
#pragma unroll
        for (int ct = 0; ct < 8; ct++)
#pragma unroll
            for (int r = 0; r < 4; r++) {
                size_t o = (size_t)(row0 + quad * 4 + r) * 128 + ct * 16 + l16;
                outL[o] = __float2bfloat16(accl[ct][r]);
                outR[o] = __float2bfloat16(accr[ct][r]);
            }
    } else {
        unsigned* hist   = (unsigned*)smem;                 // 1KB
        unsigned* lstart = (unsigned*)(smem + 1024);        // 1KB
        unsigned* lcur   = (unsigned*)(smem + 2048);        // 1KB
        unsigned* gbase  = (unsigned*)(smem + 3072);        // 1KB
        unsigned* wsum   = (unsigned*)(smem + 4096);        // 16B
        unsigned* binned = (unsigned*)(smem + 4608);        // 16KB
        unsigned* target = (unsigned*)(smem + 20992);       // 16KB
        int t = threadIdx.x;
        int e0 = ((int)blockIdx.x - GB1) * EB;
        hist[t] = 0;
        __syncthreads();
        int srcs[16], dsts[16];
#pragma unroll
        for (int i = 0; i < 16; i++) {
            int e = e0 + i * 256 + t;
            if (e < ETOT) {
                int s, d;
                if (e < NE) { s = ei[e]; d = ei[NE + e]; }
                else        { s = d = e - NE; }
                srcs[i] = s; dsts[i] = d;
                atomicAdd(&hist[d >> 8], 1u);
            } else dsts[i] = -1;
        }
        __syncthreads();
        unsigned v = hist[t];
        unsigned excl = scan256(v, wsum);
        lstart[t] = excl;
        lcur[t] = 0;
        __syncthreads();
        if (t < NBUCK && v > 0)
            gbase[t] = (unsigned)atomicAdd(&bcursor[t], (int)v) + (unsigned)t * BCAP;
        __syncthreads();
#pragma unroll
        for (int i = 0; i < 16; i++) {
            int d = dsts[i];
            if (d >= 0) {
                int bk = d >> 8;
                unsigned p = atomicAdd(&lcur[bk], 1u);
                unsigned slot = lstart[bk] + p;
                binned[slot] = ((unsigned)srcs[i] << 8) | ((unsigned)d & 255u);
                target[slot] = gbase[bk] + p;
            }
        }
        __syncthreads();
        int tot = min(EB, ETOT - e0);
        for (int s = t; s < tot; s += 256)
            tmp[target[s]] = binned[s];
    }
}

// ---- KB: per-bucket node sort -> start/deg + padded row32 (+ rare csr tails). ----
// Scattered permutation stays in LDS. row32[node][slot] = adjacency entry
// min(slot,deg-1) pre-clamps the first 32 sources per node (the node kernels'
// main paths only ever shuffle entries 0..31) so startup loads are independent.
// csr_src is written ONLY for deg>32 tail slots (the sole remaining reader).
__global__ __launch_bounds__(256) void bucket_sort(const int* __restrict__ bcursor,
                                                   const unsigned* __restrict__ tmp,
                                                   int* __restrict__ csr_src,
                                                   int* __restrict__ startA,
                                                   int* __restrict__ degA,
                                                   int* __restrict__ row32) {
    __shared__ unsigned hist[256];
    __shared__ unsigned lstart[256];
    __shared__ unsigned lcur[256];
    __shared__ unsigned wsum[4];
    __shared__ int vals[BCAP];          // 32 KB LDS staging
    int b = blockIdx.x, t = threadIdx.x;
    int cnt = bcursor[b];
    hist[t] = 0;
    __syncthreads();
    const unsigned* seg = tmp + (size_t)b * BCAP;
    for (int s = t; s < cnt; s += 256)
        atomicAdd(&hist[seg[s] & 255u], 1u);
    __syncthreads();
    unsigned v = hist[t];
    unsigned excl = scan256(v, wsum);
    lstart[t] = excl;
    lcur[t] = excl;
    int node = b * 256 + t;
    if (node < NN) {
        startA[node] = b * BCAP + (int)excl;
        degA[node] = (int)v;
    }
    __syncthreads();
    for (int s = t; s < cnt; s += 256) {
        unsigned p = seg[s];                    // L2-hot re-read
        unsigned pos = atomicAdd(&lcur[p & 255u], 1u);
        vals[pos] = (int)(p >> 8);              // scattered write stays in LDS
    }
    __syncthreads();
    // csr tails: only deg>32 slots are ever read downstream (rare)
    if (node < NN && v > 32) {
        int* cb = csr_src + (size_t)b * BCAP;
        int e2 = (int)excl;
        for (int s2 = e2 + 32; s2 < e2 + (int)v; s2++)
            cb[s2] = vals[s2];
    }
    // padded first-32 adjacency: 8 nodes per iteration (32 lanes each);
    // iteration i writes nodes [i*8, i*8+8) -> 1KB contiguous global store;
    // LDS reads are consecutive (conflict-free).
    int slot = t & 31;
#pragma unroll 4
    for (int i = 0; i < 32; i++) {
        int n2 = (t >> 5) + i * 8;
        int node2 = b * 256 + n2;
        if (node2 < NN) {
            int d2 = (int)hist[n2];
            int e2 = (int)lstart[n2];
            row32[(size_t)node2 * 32 + slot] = vals[e2 + min(slot, d2 - 1)];
        }
    }
}

// ---- K5: layer 1 fused. ONE node/wave, 16 lanes/edge, up to 32 edges in
// flight. Startup loads {deg, row32, xr} are all independent. Packed-fp32
// math: leaky(v)=0.6v+0.4|v|; log2e prefolded; accumulate w*t, -xr correct.
struct L1S { float s; f32x2 acc[4]; };
__device__ __forceinline__ void l1_consume(uint4 u, bool valid, const f32x2* xrp,
                                           const f32x2* a06, const float* a04, L1S& st) {
    f32x2 t0 = unpk2(u.x) + xrp[0];
    f32x2 t1 = unpk2(u.y) + xrp[1];
    f32x2 t2 = unpk2(u.z) + xrp[2];
    f32x2 t3 = unpk2(u.w) + xrp[3];
    f32x2 ep = t0 * a06[0];
    ep = __builtin_elementwise_fma(t1, a06[1], ep);
    ep = __builtin_elementwise_fma(t2, a06[2], ep);
    ep = __builtin_elementwise_fma(t3, a06[3], ep);
    float e0 = fmaf(a04[1], fabsf(t0.y), a04[0] * fabsf(t0.x));
    e0 = fmaf(a04[2], fabsf(t1.x), e0);
    e0 = fmaf(a04[3], fabsf(t1.y), e0);
    float e1 = fmaf(a04[5], fabsf(t2.y), a04[4] * fabsf(t2.x));
    e1 = fmaf(a04[6], fabsf(t3.x), e1);
    e1 = fmaf(a04[7], fabsf(t3.y), e1);
    float e = (ep.x + ep.y) + (e0 + e1);
    e += __shfl_xor(e, 1);
    e += __shfl_xor(e, 2);          // per-head logit (4-lane quad)
    float w = valid ? __builtin_amdgcn_exp2f(e) : 0.f;
    st.s += w;
    f32x2 wv = {w, w};
    st.acc[0] = __builtin_elementwise_fma(wv, t0, st.acc[0]);
    st.acc[1] = __builtin_elementwise_fma(wv, t1, st.acc[1]);
    st.acc[2] = __builtin_elementwise_fma(wv, t2, st.acc[2]);
    st.acc[3] = __builtin_elementwise_fma(wv, t3, st.acc[3]);
}

__global__ __launch_bounds__(256) void node_l1(const int* __restrict__ startA,
                                               const int* __restrict__ degA,
                                               const int* __restrict__ csr_src,
                                               const int* __restrict__ row32,
                                               const bf16* __restrict__ xl,
                                               const bf16* __restrict__ xr,
                                               const float* __restrict__ a1,
                                               const float* __restrict__ b1,
                                               bf16* __restrict__ hb) {
    int wid = (blockIdx.x * 256 + threadIdx.x) >> 6;
    int lane = threadIdx.x & 63;
    int g = lane >> 4, t = lane & 15;
    unsigned cB = (unsigned)t * 16;
    // three INDEPENDENT startup loads (no dependent chain)
    int deg = degA[wid];
    unsigned rowB = (unsigned)row32[((size_t)wid << 5) + (lane & 31)] << 8;
    const char* xlb = (const char*)xl;
    f32x2 xrp[4];
    {
        uint4 raw = *(const uint4*)((const char*)xr + ((unsigned)wid << 8) + cB);
        xrp[0] = unpk2(raw.x); xrp[1] = unpk2(raw.y);
        xrp[2] = unpk2(raw.z); xrp[3] = unpk2(raw.w);
    }
    f32x2 a06[4];
    float a04[8];
    {
        f32x4 lo = *reinterpret_cast<const f32x4*>(a1 + t * 8);
        f32x4 hi = *reinterpret_cast<const f32x4*>(a1 + t * 8 + 4);
        float af[8];
#pragma unroll
        for (int k = 0; k < 4; k++) { af[k] = lo[k]; af[k + 4] = hi[k]; }
#pragma unroll
        for (int j = 0; j < 4; j++) {
            a06[j].x = af[2 * j] * C06;
            a06[j].y = af[2 * j + 1] * C06;
        }
#pragma unroll
        for (int k = 0; k < 8; k++) a04[k] = af[k] * C04;
    }
    L1S st; st.s = 0.f;
    f32x2 z2 = {0.f, 0.f};
#pragma unroll
    for (int k = 0; k < 4; k++) st.acc[k] = z2;
    int nb = (deg + 3) >> 2;      // 4 edges per batch, one per 16-lane group
    uint4 u[8];
#pragma unroll
    for (int i = 0; i < 4; i++) {
        int pp = min(i * 4 + g, deg - 1);     // <= 31, shfl-safe
        u[i] = *(const uint4*)(xlb + (__shfl(rowB, pp) + cB));
    }
    if (nb > 4) {
#pragma unroll
        for (int i = 4; i < 8; i++) {
            int pp = min(i * 4 + g, deg - 1); // <= 31, shfl-safe
            u[i] = *(const uint4*)(xlb + (__shfl(rowB, pp) + cB));
        }
    }
    l1_consume(u[0], g < deg, xrp, a06, a04, st);
    if (nb > 1) l1_consume(u[1], 4 + g < deg, xrp, a06, a04, st);
    if (nb > 2) l1_consume(u[2], 8 + g < deg, xrp, a06, a04, st);
    if (nb > 3) l1_consume(u[3], 12 + g < deg, xrp, a06, a04, st);
    if (nb > 4) {
        l1_consume(u[4], 16 + g < deg, xrp, a06, a04, st);
        if (nb > 5) l1_consume(u[5], 20 + g < deg, xrp, a06, a04, st);
        if (nb > 6) l1_consume(u[6], 24 + g < deg, xrp, a06, a04, st);
        if (nb > 7) l1_consume(u[7], 28 + g < deg, xrp, a06, a04, st);
        if (nb > 8) {
            // deg > 32: rare serial fallback reads csr directly (pp >= 32).
            int j0t = startA[wid];
            for (int b = 8; b < nb; b++) {
                int p = b * 4 + g;
                bool valid = p < deg;
                int pp = valid ? p : deg - 1;       // >= 32 since deg > 32
                unsigned o = (((unsigned)csr_src[j0t + pp]) << 8) + cB;
                uint4 uu = *(const uint4*)(xlb + o);
                l1_consume(uu, valid, xrp, a06, a04, st);
            }
        }
    }
#pragma unroll
    for (int d = 16; d < 64; d <<= 1) {
        st.s += __shfl_xor(st.s, d);
#pragma unroll
        for (int k = 0; k < 4; k++) {
            st.acc[k].x += __shfl_xor(st.acc[k].x, d);
            st.acc[k].y += __shfl_xor(st.acc[k].y, d);
        }
    }
    if (g == 0) {
        float inv = 1.f / st.s;
        unsigned pk[4];
#pragma unroll
        for (int k = 0; k < 4; k++) {
            float o0 = st.acc[k].x * inv - xrp[k].x + b1[t * 8 + 2 * k];
            float o1 = st.acc[k].y * inv - xrp[k].y + b1[t * 8 + 2 * k + 1];
            o0 = o0 > 0.f ? o0 : __expf(o0) - 1.f;
            o1 = o1 > 0.f ? o1 : __expf(o1) - 1.f;
            bf16 r0 = __float2bfloat16(o0), r1 = __float2bfloat16(o1);
            pk[k] = (unsigned)*reinterpret_cast<unsigned short*>(&r0) |
                    ((unsigned)*reinterpret_cast<unsigned short*>(&r1) << 16);
        }
        uint4 w4 = {pk[0], pk[1], pk[2], pk[3]};
        *(uint4*)((char*)hb + ((unsigned)wid << 8) + cB) = w4;
    }
}

// ---- K6: GEMM2 dual (LDS-staged 24KB weights, same swizzle scheme). ----
__global__ __launch_bounds__(256) void gemm2(const bf16* __restrict__ h,
                                             const bf16* __restrict__ wT,
                                             bf16* __restrict__ outL,
                                             bf16* __restrict__ outR) {
    __shared__ __align__(16) char smem[24576];   // 96 rows x 256B
    const uint4* wsrc = (const uint4*)wT;
#pragma unroll
    for (int i = 0; i < 6; i++) {
        int idx = i * 256 + threadIdx.x;
        uint4 v = wsrc[idx];
        int r = idx >> 4;
        int c = (idx & 15) << 4;
        *(uint4*)(smem + r * 256 + (c ^ ((r & 7) << 4))) = v;
    }
    __syncthreads();
    int wave = threadIdx.x >> 6;
    int lane = threadIdx.x & 63;
    int tile = blockIdx.x * 4 + wave;
    if (tile >= MTILES) return;
    int row0 = tile * 16;
    int l16 = lane & 15, quad = lane >> 4;
    f32x4 z = {0.f, 0.f, 0.f, 0.f};
    f32x4 accl[3], accr[3];
#pragma unroll
    for (int i = 0; i < 3; i++) { accl[i] = z; accr[i] = z; }
    const bf16* hrow = h + (size_t)(row0 + l16) * 128 + quad * 8;
#pragma unroll
    for (int k0 = 0; k0 < 128; k0 += 32) {
        bf16x8 a = *reinterpret_cast<const bf16x8*>(hrow + k0);
        int cc = k0 * 2 + quad * 16;
        int sw = cc ^ ((l16 & 7) << 4);
#pragma unroll
        for (int ct = 0; ct < 3; ct++) {
            int rl = ct * 16 + l16;
            bf16x8 bl = *(const bf16x8*)(smem + rl * 256 + sw);
            bf16x8 br = *(const bf16x8*)(smem + 12288 + rl * 256 + sw);
            accl[ct] = __builtin_amdgcn_mfma_f32_16x16x32_bf16(a, bl, accl[ct], 0, 0, 0);
            accr[ct] = __builtin_amdgcn_mfma_f32_16x16x32_bf16(a, br, accr[ct], 0, 0, 0);
        }
    }
#pragma unroll
    for (int ct = 0; ct < 3; ct++)
#pragma unroll
        for (int r = 0; r < 4; r++) {
            size_t o = (size_t)(row0 + quad * 4 + r) * CLSP + ct * 16 + l16;
            outL[o] = __float2bfloat16(accl[ct][r]);
            outR[o] = __float2bfloat16(accr[ct][r]);
        }
}

// ---- K7: layer 2 fused. TWO nodes per wave (measured-best for l2), 8 lanes/edge.
// row32 removes the startA->csr chain here too.
struct L2S { float s; f32x2 acc[3]; };
__device__ __forceinline__ void l2_consume(U3 u, bool valid, const f32x2* xrp,
                                           const f32x2* a06, const float* a04, L2S& st) {
    f32x2 t0 = unpk2(u.x) + xrp[0];
    f32x2 t1 = unpk2(u.y) + xrp[1];
    f32x2 t2 = unpk2(u.z) + xrp[2];
    f32x2 ep = t0 * a06[0];
    ep = __builtin_elementwise_fma(t1, a06[1], ep);
    ep = __builtin_elementwise_fma(t2, a06[2], ep);
    float es = fmaf(a04[1], fabsf(t0.y), a04[0] * fabsf(t0.x));
    es = fmaf(a04[2], fabsf(t1.x), es);
    es = fmaf(a04[3], fabsf(t1.y), es);
    es = fmaf(a04[4], fabsf(t2.x), es);
    es = fmaf(a04[5], fabsf(t2.y), es);
    float e = (ep.x + ep.y) + es;
    e += __shfl_xor(e, 1);
    e += __shfl_xor(e, 2);
    e += __shfl_xor(e, 4);          // full 48-ch logit (8-lane group)
    float w = valid ? __builtin_amdgcn_exp2f(e) : 0.f;
    st.s += w;
    f32x2 wv = {w, w};
    st.acc[0] = __builtin_elementwise_fma(wv, t0, st.acc[0]);
    st.acc[1] = __builtin_elementwise_fma(wv, t1, st.acc[1]);
    st.acc[2] = __builtin_elementwise_fma(wv, t2, st.acc[2]);
}

__global__ __launch_bounds__(256) void node_l2(const int* __restrict__ startA,
                                               const int* __restrict__ degA,
                                               const int* __restrict__ csr_src,
                                               const int* __restrict__ row32,
                                               const bf16* __restrict__ xl2,
                                               const bf16* __restrict__ xr2,
                                               const float* __restrict__ a2,
                                               const float* __restrict__ b2,
                                               float* __restrict__ out) {
    int wv = (blockIdx.x * 256 + threadIdx.x) >> 6;
    int n0 = wv * 2, n1 = n0 + 1;
    int lane = threadIdx.x & 63;
    int g = lane >> 3, t = lane & 7;
    unsigned cB = (unsigned)t * 12;
    const char* xlb = (const char*)xl2;
    int c = t * 6;
    f32x2 a06[3];
    float a04[6], bv[6];
#pragma unroll
    for (int k = 0; k < 6; k++) {
        bool val = (c + k < CLS);
        float av = val ? a2[c + k] : 0.f;
        bv[k] = val ? b2[c + k] : 0.f;
        a04[k] = av * C04;
        if (k & 1) a06[k >> 1].y = av * C06; else a06[k >> 1].x = av * C06;
    }
    // independent startup loads for both nodes
    int dega = degA[n0], degb = degA[n1];
    unsigned rowBa = (unsigned)row32[((size_t)n0 << 5) + (lane & 31)] * 96u;
    unsigned rowBb = (unsigned)row32[((size_t)n1 << 5) + (lane & 31)] * 96u;
    f32x2 xra[3], xrb[3];
    {
        U3 ra = *(const U3*)((const char*)xr2 + (unsigned)n0 * 96u + cB);
        U3 rb = *(const U3*)((const char*)xr2 + (unsigned)n1 * 96u + cB);
        xra[0] = unpk2(ra.x); xra[1] = unpk2(ra.y); xra[2] = unpk2(ra.z);
        xrb[0] = unpk2(rb.x); xrb[1] = unpk2(rb.y); xrb[2] = unpk2(rb.z);
    }
    int nba = (dega + 7) >> 3, nbb = (degb + 7) >> 3;
    U3 ua[2], ub[2];
#pragma unroll
    for (int i = 0; i < 2; i++)
        ua[i] = *(const U3*)(xlb + (__shfl(rowBa, min(i * 8 + g, dega - 1)) + cB));
#pragma unroll
    for (int i = 0; i < 2; i++)
        ub[i] = *(const U3*)(xlb + (__shfl(rowBb, min(i * 8 + g, degb - 1)) + cB));
    L2S sa, sb;
    f32x2 z2 = {0.f, 0.f};
    sa.s = 0.f; sb.s = 0.f;
#pragma unroll
    for (int k = 0; k < 3; k++) { sa.acc[k] = z2; sb.acc[k] = z2; }
    // consume A round 1 (B's loads still in flight)
    l2_consume(ua[0], g < dega, xra, a06, a04, sa);
    if (nba > 1) l2_consume(ua[1], 8 + g < dega, xra, a06, a04, sa);
    U3 ua2[2];
    if (nba > 2) {
#pragma unroll
        for (int i = 0; i < 2; i++)
            ua2[i] = *(const U3*)(xlb + (__shfl(rowBa, min((i + 2) * 8 + g, dega - 1)) + cB));
    }
    // consume B round 1
    l2_consume(ub[0], g < degb, xrb, a06, a04, sb);
    if (nbb > 1) l2_consume(ub[1], 8 + g < degb, xrb, a06, a04, sb);
    U3 ub2[2];
    if (nbb > 2) {
#pragma unroll
        for (int i = 0; i < 2; i++)
            ub2[i] = *(const U3*)(xlb + (__shfl(rowBb, min((i + 2) * 8 + g, degb - 1)) + cB));
    }
    if (nba > 2) {
        l2_consume(ua2[0], 16 + g < dega, xra, a06, a04, sa);
        if (nba > 3) l2_consume(ua2[1], 24 + g < dega, xra, a06, a04, sa);
        if (nba > 4) {
            // deg > 32: rare serial fallback reads csr directly (pp >= 32).
            int j0a = startA[n0];
            for (int b = 4; b < nba; b++) {
                int p = b * 8 + g;
                bool valid = p < dega;
                int pp = valid ? p : dega - 1;      // >= 32 since dega > 32
                unsigned o = (unsigned)csr_src[j0a + pp] * 96u + cB;
                U3 uu = *(const U3*)(xlb + o);
                l2_consume(uu, valid, xra, a06, a04, sa);
            }
        }
    }
    if (nbb > 2) {
        l2_consume(ub2[0], 16 + g < degb, xrb, a06, a04, sb);
        if (nbb > 3) l2_consume(ub2[1], 24 + g < degb, xrb, a06, a04, sb);
        if (nbb > 4) {
            int j0b = startA[n1];
            for (int b = 4; b < nbb; b++) {
                int p = b * 8 + g;
                bool valid = p < degb;
                int pp = valid ? p : degb - 1;      // >= 32 since degb > 32
                unsigned o = (unsigned)csr_src[j0b + pp] * 96u + cB;
                U3 uu = *(const U3*)(xlb + o);
                l2_consume(uu, valid, xrb, a06, a04, sb);
            }
        }
    }
#pragma unroll
    for (int d = 8; d < 64; d <<= 1) {
        sa.s += __shfl_xor(sa.s, d);
        sb.s += __shfl_xor(sb.s, d);
#pragma unroll
        for (int k = 0; k < 3; k++) {
            sa.acc[k].x += __shfl_xor(sa.acc[k].x, d);
            sa.acc[k].y += __shfl_xor(sa.acc[k].y, d);
            sb.acc[k].x += __shfl_xor(sb.acc[k].x, d);
            sb.acc[k].y += __shfl_xor(sb.acc[k].y, d);
        }
    }
    // epilogue A
    {
        float inv = 1.f / sa.s;
        float q[6];
        float mx = -3e38f;
#pragma unroll
        for (int k = 0; k < 6; k++) {
            bool val = (c + k < CLS);
            float av = (k & 1) ? sa.acc[k >> 1].y : sa.acc[k >> 1].x;
            float xv = (k & 1) ? xra[k >> 1].y : xra[k >> 1].x;
            q[k] = val ? (av * inv - xv + bv[k]) : -3e38f;
            mx = fmaxf(mx, q[k]);
        }
        mx = fmaxf(mx, __shfl_xor(mx, 1));
        mx = fmaxf(mx, __shfl_xor(mx, 2));
        mx = fmaxf(mx, __shfl_xor(mx, 4));
        float se = 0.f;
#pragma unroll
        for (int k = 0; k < 6; k++) if (c + k < CLS) se += __expf(q[k] - mx);
        se += __shfl_xor(se, 1);
        se += __shfl_xor(se, 2);
        se += __shfl_xor(se, 4);
        float ls = mx + __logf(se);
        if (g == 0) {
            float* o = out + (size_t)n0 * CLS + c;
#pragma unroll
            for (int k = 0; k < 6; k++)
                if (c + k < CLS) o[k] = q[k] - ls;
        }
    }
    // epilogue B
    {
        float inv = 1.f / sb.s;
        float q[6];
        float mx = -3e38f;
#pragma unroll
        for (int k = 0; k < 6; k++) {
            bool val = (c + k < CLS);
            float av = (k & 1) ? sb.acc[k >> 1].y : sb.acc[k >> 1].x;
            float xv = (k & 1) ? xrb[k >> 1].y : xrb[k >> 1].x;
            q[k] = val ? (av * inv - xv + bv[k]) : -3e38f;
            mx = fmaxf(mx, q[k]);
        }
        mx = fmaxf(mx, __shfl_xor(mx, 1));
        mx = fmaxf(mx, __shfl_xor(mx, 2));
        mx = fmaxf(mx, __shfl_xor(mx, 4));
        float se = 0.f;
#pragma unroll
        for (int k = 0; k < 6; k++) if (c + k < CLS) se += __expf(q[k] - mx);
        se += __shfl_xor(se, 1);
        se += __shfl_xor(se, 2);
        se += __shfl_xor(se, 4);
        float ls = mx + __logf(se);
        if (g == 0) {
            float* o = out + (size_t)n1 * CLS + c;
#pragma unroll
            for (int k = 0; k < 6; k++)
                if (c + k < CLS) o[k] = q[k] - ls;
        }
    }
}

extern "C" void kernel_launch(void* const* d_in, const int* in_sizes, int n_in,
                              void* d_out, int out_size, void* d_ws, size_t ws_size,
                              hipStream_t stream) {
    const float* x   = (const float*)d_in[0];
    const int*   ei  = (const int*)d_in[1];
    const float* w1l = (const float*)d_in[2];
    const float* w1r = (const float*)d_in[3];
    const float* a1  = (const float*)d_in[4];
    const float* b1  = (const float*)d_in[5];
    const float* w2l = (const float*)d_in[6];
    const float* w2r = (const float*)d_in[7];
    const float* a2  = (const float*)d_in[8];
    const float* b2  = (const float*)d_in[9];
    float* out = (float*)d_out;

    // Workspace layout (total ~67.7 MB):
    char* base = (char*)d_ws;
    int*      bcursor = (int*)(base + 0);            //       784 B (zeroed by prep)
    int*      startA  = (int*)(base + 1024);         //   200,000 B
    int*      degA    = (int*)(base + 201024);       //   200,000 B
    unsigned* tmp     = (unsigned*)(base + 401024);  //  6,422,528 B (NBUCK*BCAP*4, packed)
    int*      csr_src = (int*)(base + 6823552);      //  6,422,528 B (tails only)
    bf16*     xl1     = (bf16*)(base + 13246080);    // 25,600,000 B (xl1|xr1)
    bf16*     hb      = (bf16*)(base + 38846080);    // 12,800,000 B
    bf16*     xl2p    = (bf16*)(base + 51646080);    //  9,600,000 B (xl2p|xr2p, stride 48)
    bf16*     wT1     = (bf16*)(base + 61246080);    //     65,536 B
    bf16*     wT2     = (bf16*)(base + 61311616);    //     24,576 B
    int*      row32   = (int*)(base + 61336192);     //  6,400,000 B (NN*32*4)
    bf16* xr1  = xl1 + (size_t)NN * 128;
    bf16* xr2p = xl2p + (size_t)NN * CLSP;

    prep<<<PREPB, 256, 0, stream>>>(w1l, w1r, w2l, w2r, wT1, wT2, bcursor);
    gemm1_scatter<<<GB1 + KAB, 256, 0, stream>>>(x, wT1, xl1, xr1, ei, bcursor, tmp);
    bucket_sort<<<NBUCK, 256, 0, stream>>>(bcursor, tmp, csr_src, startA, degA, row32);
    node_l1<<<(NN * 64) / 256, 256, 0, stream>>>(startA, degA, csr_src, row32, xl1, xr1, a1, b1, hb);
    gemm2<<<GB1, 256, 0, stream>>>(hb, wT2, xl2p, xr2p);
    node_l2<<<NODEB, 256, 0, stream>>>(startA, degA, csr_src, row32, xl2p, xr2p, a2, b2, out);
}